// Round 6
// baseline (624.466 us; speedup 1.0000x reference)
//
#include <hip/hip_runtime.h>
#include <math.h>

// ---------------------------------------------------------------------------
// Bidirectional Mamba encoder, fp32, round 6.
// - GEMM kernels: LDS double-buffered k-loop (one barrier/iter, prefetch in
//   registers bounded by #pragma unroll 1 -- avoids round-2 spill).
// - k_embed: split-K=4 (grid 33x8x4, 4 blocks/CU) + fp32 atomicAdd into
//   zero-initialized H (hipMemsetAsync); bias added by chunk 0.
// - k_out/k_ffn back to 32-row tiles with 2x8 per-thread fragments.
// - Scan: round-5 two-pass chunked scan (16 chunks, DPP reduce) unchanged.
// ---------------------------------------------------------------------------

#define L_SEQ 1031
#define LP    1088          // 16 chunks x 68
#define TC    68
#define NCH   16
#define BATCH 8
#define NVAR  1024
#define SEQQ  512
#define TFEAT 7

#define SZ_H    ((size_t)BATCH * L_SEQ * 128)
#define SZ_XZ   ((size_t)2 * BATCH * L_SEQ * 256)
#define SZ_DT   ((size_t)2 * BATCH * 128 * LP)
#define SZ_BC   ((size_t)2 * BATCH * 16 * LP)
#define OFF_H    ((size_t)0)
#define OFF_H1   (OFF_H + SZ_H)
#define OFF_XZ   (OFF_H1 + SZ_H)
#define OFF_XCT  (OFF_XZ + SZ_XZ)
#define OFF_DLT  (OFF_XCT + SZ_DT)
#define OFF_BMT  (OFF_DLT + SZ_DT)
#define OFF_CMT  (OFF_BMT + SZ_BC)
#define OFF_YT   (OFF_CMT + SZ_BC)
#define SZ_SUM  ((size_t)2 * BATCH * NCH * 128 * 16)   // 524,288 floats

__device__ __forceinline__ float silu_f(float x) {
  return x / (1.f + __expf(-x));
}
__device__ __forceinline__ float softplus_f(float x) {
  return (x > 20.f) ? x : log1pf(__expf(x));
}
__device__ __forceinline__ float red8(float x) {
  x += __int_as_float(__builtin_amdgcn_update_dpp(
      0, __float_as_int(x), 0xB1, 0xF, 0xF, true));   // quad_perm [1,0,3,2]
  x += __int_as_float(__builtin_amdgcn_update_dpp(
      0, __float_as_int(x), 0x4E, 0xF, 0xF, true));   // quad_perm [2,3,0,1]
  x += __int_as_float(__builtin_amdgcn_update_dpp(
      0, __float_as_int(x), 0x141, 0xF, 0xF, true));  // row_half_mirror
  return x;
}

// 2 rows x (4+4) cols per thread; AS/WS are pointers to [36]/[132] rows.
#define GEMM_INNER(AS, WS, ACC)                                   \
  _Pragma("unroll")                                               \
  for (int k = 0; k < 32; k++) {                                  \
    float2 a = *(const float2*)&AS[k][tt * 2];                    \
    float4 w0 = *(const float4*)&WS[k][tm * 4];                   \
    float4 w1 = *(const float4*)&WS[k][64 + tm * 4];              \
    ACC[0][0] = fmaf(a.x, w0.x, ACC[0][0]);                       \
    ACC[0][1] = fmaf(a.x, w0.y, ACC[0][1]);                       \
    ACC[0][2] = fmaf(a.x, w0.z, ACC[0][2]);                       \
    ACC[0][3] = fmaf(a.x, w0.w, ACC[0][3]);                       \
    ACC[0][4] = fmaf(a.x, w1.x, ACC[0][4]);                       \
    ACC[0][5] = fmaf(a.x, w1.y, ACC[0][5]);                       \
    ACC[0][6] = fmaf(a.x, w1.z, ACC[0][6]);                       \
    ACC[0][7] = fmaf(a.x, w1.w, ACC[0][7]);                       \
    ACC[1][0] = fmaf(a.y, w0.x, ACC[1][0]);                       \
    ACC[1][1] = fmaf(a.y, w0.y, ACC[1][1]);                       \
    ACC[1][2] = fmaf(a.y, w0.z, ACC[1][2]);                       \
    ACC[1][3] = fmaf(a.y, w0.w, ACC[1][3]);                       \
    ACC[1][4] = fmaf(a.y, w1.x, ACC[1][4]);                       \
    ACC[1][5] = fmaf(a.y, w1.y, ACC[1][5]);                       \
    ACC[1][6] = fmaf(a.y, w1.z, ACC[1][6]);                       \
    ACC[1][7] = fmaf(a.y, w1.w, ACC[1][7]);                       \
  }

// commit staged registers to LDS buffers (A: 1 float4 along 4 k's for (row);
// W: 4 float4 along 4 k's for (n))
#define COMMIT_A(AB, AV)                 \
  {                                      \
    AB[k4 * 4 + 0][row] = (AV).x;        \
    AB[k4 * 4 + 1][row] = (AV).y;        \
    AB[k4 * 4 + 2][row] = (AV).z;        \
    AB[k4 * 4 + 3][row] = (AV).w;        \
  }
#define COMMIT_W(WB, WV)                 \
  _Pragma("unroll")                      \
  for (int i_ = 0; i_ < 4; i_++) {       \
    int e_ = tid + i_ * 256;             \
    int n_ = e_ >> 3, kk_ = e_ & 7;      \
    WB[kk_ * 4 + 0][n_] = (WV)[i_].x;    \
    WB[kk_ * 4 + 1][n_] = (WV)[i_].y;    \
    WB[kk_ * 4 + 2][n_] = (WV)[i_].z;    \
    WB[kk_ * 4 + 3][n_] = (WV)[i_].w;    \
  }

// ---------------------------------------------------------------------------
// k_embed (split-K): partial H[b,v,:] += token(b,v,s0..s0+127) @ emb_w.T
// grid (33, 8, 4) z = K-chunk, block 256, 32v x 128m tiles, dbuf.
// H must be zeroed before launch; chunk 0 adds emb_b.
// ---------------------------------------------------------------------------
__global__ __launch_bounds__(256) void k_embed(
    const float* __restrict__ x_enc, const float* __restrict__ x_mark,
    const float* __restrict__ emb_w, const float* __restrict__ emb_b,
    float* __restrict__ H) {
  int b = blockIdx.y;
  int v0 = blockIdx.x * 32;
  int sbase = blockIdx.z * 128;
  int tid = threadIdx.x;
  int tm = tid & 15, tt = tid >> 4;
  __shared__ float As[2][32][36];    // [s][v]
  __shared__ float Ws[2][32][132];   // [s][m]
  float acc[2][8] = {{0.f}};
  int row = tid >> 3, k4 = tid & 7;  // A: row = s-index(32), k4 = v-group(8)

  float4 aN;
  float4 wN[4];
#define LOAD_EMB_A(S0)                                                        \
  {                                                                           \
    int vg = v0 + k4 * 4;                                                     \
    int s = (S0) + row;                                                       \
    if (vg + 3 < NVAR) {                                                      \
      aN = *(const float4*)&x_enc[((size_t)b * SEQQ + s) * NVAR + vg];        \
      if (aN.x == -9999.f) aN.x = -1.f;                                       \
      if (aN.y == -9999.f) aN.y = -1.f;                                       \
      if (aN.z == -9999.f) aN.z = -1.f;                                       \
      if (aN.w == -9999.f) aN.w = -1.f;                                       \
    } else {                                                                  \
      float tmp[4];                                                           \
      _Pragma("unroll")                                                       \
      for (int u = 0; u < 4; u++) {                                           \
        int v = vg + u;                                                       \
        tmp[u] = 0.f;                                                         \
        if (v < L_SEQ)                                                        \
          tmp[u] = x_mark[((size_t)b * SEQQ + s) * TFEAT + (v - NVAR)];       \
      }                                                                       \
      aN = make_float4(tmp[0], tmp[1], tmp[2], tmp[3]);                       \
    }                                                                         \
  }
#define LOAD_EMB_W(S0)                                                        \
  _Pragma("unroll")                                                           \
  for (int i_ = 0; i_ < 4; i_++) {                                            \
    int e_ = tid + i_ * 256;                                                  \
    int m_ = e_ >> 3, kk_ = e_ & 7;                                           \
    wN[i_] = *(const float4*)&emb_w[(size_t)m_ * SEQQ + (S0) + kk_ * 4];      \
  }

  LOAD_EMB_A(sbase);
  LOAD_EMB_W(sbase);
  {
    // A commit uses (s=row, v=k4*4..): direct layout
    As[0][row][k4 * 4 + 0] = aN.x;
    As[0][row][k4 * 4 + 1] = aN.y;
    As[0][row][k4 * 4 + 2] = aN.z;
    As[0][row][k4 * 4 + 3] = aN.w;
  }
  COMMIT_W(Ws[0], wN);
#pragma unroll 1
  for (int kt = 0; kt < 4; kt++) {
    __syncthreads();
    int cur = kt & 1;
    bool more = (kt + 1) < 4;
    if (more) {
      int s0 = sbase + (kt + 1) * 32;
      LOAD_EMB_A(s0);
      LOAD_EMB_W(s0);
    }
    GEMM_INNER(As[cur], Ws[cur], acc);
    if (more) {
      int nb = (kt + 1) & 1;
      As[nb][row][k4 * 4 + 0] = aN.x;
      As[nb][row][k4 * 4 + 1] = aN.y;
      As[nb][row][k4 * 4 + 2] = aN.z;
      As[nb][row][k4 * 4 + 3] = aN.w;
      COMMIT_W(Ws[nb], wN);
    }
  }
#undef LOAD_EMB_A
#undef LOAD_EMB_W
  bool addb = (blockIdx.z == 0);
#pragma unroll
  for (int r = 0; r < 2; r++) {
    int v = v0 + tt * 2 + r;
    if (v < L_SEQ) {
      float* dst = &H[((size_t)b * L_SEQ + v) * 128];
#pragma unroll
      for (int j = 0; j < 4; j++) {
        float b0 = addb ? emb_b[tm * 4 + j] : 0.f;
        float b1 = addb ? emb_b[64 + tm * 4 + j] : 0.f;
        atomicAdd(&dst[tm * 4 + j], acc[r][j] + b0);
        atomicAdd(&dst[64 + tm * 4 + j], acc[r][4 + j] + b1);
      }
    }
  }
}

// ---------------------------------------------------------------------------
// k_xz: XZ[dir,b,t,nh*128:+128] = h_dir(b,t,:) @ ipw[l,dir,nh].T
// grid (33, 8, 4) z=(dir,nh), block 256, dbuf k-loop.
// ---------------------------------------------------------------------------
__global__ __launch_bounds__(256) void k_xz(
    const float* __restrict__ H, const float* __restrict__ ipw,
    float* __restrict__ XZ, int l) {
  int b = blockIdx.y;
  int dir = blockIdx.z >> 1, nh = blockIdx.z & 1;
  int t0 = blockIdx.x * 32;
  int tid = threadIdx.x;
  int tm = tid & 15, tt = tid >> 4;
  __shared__ float As[2][32][36];
  __shared__ float Ws[2][32][132];
  float acc[2][8] = {{0.f}};
  const float* wbase = ipw + (size_t)(l * 2 + dir) * 256 * 128 + (size_t)nh * 128 * 128;
  int row = tid >> 3, k4 = tid & 7;
  int t = t0 + row;
  int st = dir ? (L_SEQ - 1 - t) : t;
  bool tin = (t < L_SEQ);

  float4 aN;
  float4 wN[4];
#define LOAD_XZ_A(K0)                                                         \
  {                                                                           \
    aN = make_float4(0.f, 0.f, 0.f, 0.f);                                     \
    if (tin)                                                                  \
      aN = *(const float4*)&H[((size_t)b * L_SEQ + st) * 128 + (K0) + k4 * 4];\
  }
#define LOAD_XZ_W(K0)                                                         \
  _Pragma("unroll")                                                           \
  for (int i_ = 0; i_ < 4; i_++) {                                            \
    int e_ = tid + i_ * 256;                                                  \
    int n_ = e_ >> 3, kk_ = e_ & 7;                                           \
    wN[i_] = *(const float4*)&wbase[(size_t)n_ * 128 + (K0) + kk_ * 4];       \
  }
  LOAD_XZ_A(0);
  LOAD_XZ_W(0);
  COMMIT_A(As[0], aN);
  COMMIT_W(Ws[0], wN);
#pragma unroll 1
  for (int kt = 0; kt < 4; kt++) {
    __syncthreads();
    int cur = kt & 1;
    bool more = (kt + 1) < 4;
    if (more) {
      int k0 = (kt + 1) * 32;
      LOAD_XZ_A(k0);
      LOAD_XZ_W(k0);
    }
    GEMM_INNER(As[cur], Ws[cur], acc);
    if (more) {
      int nb = (kt + 1) & 1;
      COMMIT_A(As[nb], aN);
      COMMIT_W(Ws[nb], wN);
    }
  }
#undef LOAD_XZ_A
#undef LOAD_XZ_W
#pragma unroll
  for (int r = 0; r < 2; r++) {
    int to = t0 + tt * 2 + r;
    if (to < L_SEQ) {
      float* dst = XZ + ((size_t)(dir * BATCH + b) * L_SEQ + to) * 256 + nh * 128;
      *(float4*)&dst[tm * 4] = *(float4*)&acc[r][0];
      *(float4*)&dst[64 + tm * 4] = *(float4*)&acc[r][4];
    }
  }
}

// ---------------------------------------------------------------------------
// k_mid  (round-3, proven; grid (34,8,2) covers LP=1088)
// ---------------------------------------------------------------------------
__global__ __launch_bounds__(256) void k_mid(
    const float* __restrict__ XZ,
    const float* __restrict__ conv_w, const float* __restrict__ conv_b,
    const float* __restrict__ xpw,
    const float* __restrict__ dpw, const float* __restrict__ dpb,
    float* __restrict__ XCT, float* __restrict__ DLT,
    float* __restrict__ BmT, float* __restrict__ CmT, int l) {
  int b = blockIdx.y, dir = blockIdx.z;
  int t0 = blockIdx.x * 32;
  int tid = threadIdx.x;
  int pg = l * 2 + dir;
  __shared__ float xcs[32][132];
  __shared__ float xpws[40][128];
  __shared__ float dbcs[40][36];
  const float* xz = XZ + (size_t)(dir * BATCH + b) * L_SEQ * 256;

  for (int i = 0; i < 20; i++) {
    int e = tid + i * 256;
    int k = e & 127, j = e >> 7;
    xpws[j][k] = xpw[((size_t)pg * 40 + j) * 128 + k];
  }
  for (int i = 0; i < 16; i++) {
    int e = tid + i * 256;
    int d = e & 127, tl = e >> 7;
    int t = t0 + tl;
    float v = 0.f;
    if (t < L_SEQ) {
      float x1 = xz[(size_t)t * 256 + d];
      float x0 = (t > 0) ? xz[(size_t)(t - 1) * 256 + d] : 0.f;
      float c0 = conv_w[((size_t)pg * 128 + d) * 2 + 0];
      float c1 = conv_w[((size_t)pg * 128 + d) * 2 + 1];
      v = silu_f(x0 * c0 + x1 * c1 + conv_b[(size_t)pg * 128 + d]);
    }
    xcs[tl][d] = v;
  }
  __syncthreads();
  {
    int tl = tid & 31, jg = tid >> 5;
    float acc[5] = {0.f};
    const float4* xrow = (const float4*)&xcs[tl][0];
    for (int kk = 0; kk < 32; kk++) {
      float4 a = xrow[kk];
#pragma unroll
      for (int jj = 0; jj < 5; jj++) {
        float4 w = ((const float4*)&xpws[jg * 5 + jj][0])[kk];
        acc[jj] = fmaf(a.x, w.x, acc[jj]);
        acc[jj] = fmaf(a.y, w.y, acc[jj]);
        acc[jj] = fmaf(a.z, w.z, acc[jj]);
        acc[jj] = fmaf(a.w, w.w, acc[jj]);
      }
    }
#pragma unroll
    for (int jj = 0; jj < 5; jj++) dbcs[jg * 5 + jj][tl] = acc[jj];
  }
  __syncthreads();
  for (int i = 0; i < 4; i++) {
    int e = tid + i * 256;
    int tl = e & 31, r = e >> 5;
    int n = r & 15, isC = r >> 4;
    int t = t0 + tl;
    if (t < LP) {
      float v = dbcs[8 + isC * 16 + n][tl];
      float* dst = isC ? CmT : BmT;
      dst[((size_t)(dir * BATCH + b) * 16 + n) * LP + t] = v;
    }
  }
  {
    int d = tid & 127, th = tid >> 7;
    float dw[8];
#pragma unroll
    for (int k = 0; k < 8; k++) dw[k] = dpw[((size_t)pg * 128 + d) * 8 + k];
    float dbv = dpb[(size_t)pg * 128 + d];
    size_t base = ((size_t)(dir * BATCH + b) * 128 + d) * LP;
    for (int tb = th * 16; tb < th * 16 + 16; tb += 4) {
      int t = t0 + tb;
      if (t < LP) {
        float dv[4], xv[4];
#pragma unroll
        for (int u = 0; u < 4; u++) {
          int tl = tb + u;
          float a = dbv;
#pragma unroll
          for (int k = 0; k < 8; k++) a = fmaf(dbcs[k][tl], dw[k], a);
          dv[u] = softplus_f(a);
          xv[u] = xcs[tl][d];
        }
        *(float4*)(DLT + base + t) = make_float4(dv[0], dv[1], dv[2], dv[3]);
        *(float4*)(XCT + base + t) = make_float4(xv[0], xv[1], xv[2], xv[3]);
      }
    }
  }
}

// ---------------------------------------------------------------------------
// k_scan1  (round-5, proven)
// ---------------------------------------------------------------------------
__global__ __launch_bounds__(64) void k_scan1(
    const float* __restrict__ DLT, const float* __restrict__ XCT,
    const float* __restrict__ BmT,
    const float* __restrict__ A_log,
    float* __restrict__ sumH, float* __restrict__ sumP, int l) {
  int z = blockIdx.z;
  int dir = z >> 4, j = z & 15;
  int b = blockIdx.y;
  int lane = threadIdx.x;
  int np = lane & 7, ds = lane >> 3;
  int d = blockIdx.x * 8 + ds;
  int pg = l * 2 + dir;
  int n0 = np * 2;
  float A0 = -__expf(A_log[((size_t)pg * 128 + d) * 16 + n0]);
  float A1 = -__expf(A_log[((size_t)pg * 128 + d) * 16 + n0 + 1]);
  size_t bd = ((size_t)(dir * BATCH + b) * 128 + d) * LP + (size_t)j * TC;
  size_t bn = ((size_t)(dir * BATCH + b) * 16 + n0) * LP + (size_t)j * TC;
  const float4* dl4 = (const float4*)(DLT + bd);
  const float4* xc4 = (const float4*)(XCT + bd);
  const float4* b04 = (const float4*)(BmT + bn);
  const float4* b14 = (const float4*)(BmT + bn + LP);
  float h0 = 0.f, h1 = 0.f, sdl = 0.f;
  const int NI = TC / 4;   // 17
  float4 cd = dl4[0], cx = xc4[0], cb0 = b04[0], cb1 = b14[0];
#define P1STEP(DL, XC, B0, B1)                       \
  {                                                  \
    float du_ = (DL) * (XC);                         \
    h0 = fmaf(__expf((DL) * A0), h0, du_ * (B0));    \
    h1 = fmaf(__expf((DL) * A1), h1, du_ * (B1));    \
  }
  for (int i = 0; i < NI; i++) {
    float4 nd = cd, nx = cx, nb0 = cb0, nb1 = cb1;
    if (i + 1 < NI) {
      nd = dl4[i + 1]; nx = xc4[i + 1];
      nb0 = b04[i + 1]; nb1 = b14[i + 1];
    }
    P1STEP(cd.x, cx.x, cb0.x, cb1.x);
    P1STEP(cd.y, cx.y, cb0.y, cb1.y);
    P1STEP(cd.z, cx.z, cb0.z, cb1.z);
    P1STEP(cd.w, cx.w, cb0.w, cb1.w);
    sdl += (cd.x + cd.y) + (cd.z + cd.w);
    cd = nd; cx = nx; cb0 = nb0; cb1 = nb1;
  }
#undef P1STEP
  size_t si = (((size_t)(dir * BATCH + b) * NCH + j) * 128 + d) * 16 + n0;
  *(float2*)&sumH[si] = make_float2(h0, h1);
  *(float2*)&sumP[si] = make_float2(__expf(A0 * sdl), __expf(A1 * sdl));
}

// ---------------------------------------------------------------------------
// k_scan2  (round-5, proven)
// ---------------------------------------------------------------------------
__global__ __launch_bounds__(64) void k_scan2(
    const float* __restrict__ DLT, const float* __restrict__ XCT,
    const float* __restrict__ BmT, const float* __restrict__ CmT,
    const float* __restrict__ XZ,
    const float* __restrict__ A_log, const float* __restrict__ Dpar,
    const float* __restrict__ sumH, const float* __restrict__ sumP,
    float* __restrict__ YT, int l) {
  int z = blockIdx.z;
  int dir = z >> 4, j = z & 15;
  int b = blockIdx.y;
  int lane = threadIdx.x;
  int np = lane & 7, ds = lane >> 3;
  int d = blockIdx.x * 8 + ds;
  int pg = l * 2 + dir;
  int n0 = np * 2;
  float A0 = -__expf(A_log[((size_t)pg * 128 + d) * 16 + n0]);
  float A1 = -__expf(A_log[((size_t)pg * 128 + d) * 16 + n0 + 1]);
  float Dv = Dpar[(size_t)pg * 128 + d];
  float h0 = 0.f, h1 = 0.f;
  {
    size_t sbase = ((size_t)(dir * BATCH + b) * NCH) * 2048 + (size_t)d * 16 + n0;
    for (int jj = 0; jj < j; jj++) {
      float2 hE = *(const float2*)&sumH[sbase + (size_t)jj * 2048];
      float2 Pp = *(const float2*)&sumP[sbase + (size_t)jj * 2048];
      h0 = fmaf(Pp.x, h0, hE.x);
      h1 = fmaf(Pp.y, h1, hE.y);
    }
  }
  size_t bd = ((size_t)(dir * BATCH + b) * 128 + d) * LP + (size_t)j * TC;
  size_t bn = ((size_t)(dir * BATCH + b) * 16 + n0) * LP + (size_t)j * TC;
  const float4* dl4 = (const float4*)(DLT + bd);
  const float4* xc4 = (const float4*)(XCT + bd);
  const float4* b04 = (const float4*)(BmT + bn);
  const float4* b14 = (const float4*)(BmT + bn + LP);
  const float4* c04 = (const float4*)(CmT + bn);
  const float4* c14 = (const float4*)(CmT + bn + LP);
  const float* zbase = XZ + (size_t)(dir * BATCH + b) * L_SEQ * 256 + 128 + d
                       + (size_t)j * TC * 256;
  float4* y4 = (float4*)(YT + bd);
  const int NI = TC / 4;   // 17
  float4 cd = dl4[0], cx = xc4[0], cb0 = b04[0], cb1 = b14[0];
  float4 cc0 = c04[0], cc1 = c14[0];
  float zc[4], zn[4];
  if (np == 0) {
#pragma unroll
    for (int u = 0; u < 4; u++) zc[u] = zbase[(size_t)u * 256];
  }
#define STEP1(DL, XC, B0, B1, C0, C1, YO)            \
  {                                                  \
    float du_ = (DL) * (XC);                         \
    h0 = fmaf(__expf((DL) * A0), h0, du_ * (B0));    \
    h1 = fmaf(__expf((DL) * A1), h1, du_ * (B1));    \
    float p_ = red8(fmaf(h1, (C1), h0 * (C0)));      \
    (YO) = fmaf(Dv, (XC), p_);                       \
  }
  for (int i = 0; i < NI; i++) {
    float4 nd = cd, nx = cx, nb0 = cb0, nb1 = cb1, nc0 = cc0, nc1 = cc1;
    if (i + 1 < NI) {
      nd = dl4[i + 1]; nx = xc4[i + 1];
      nb0 = b04[i + 1]; nb1 = b14[i + 1];
      nc0 = c04[i + 1]; nc1 = c14[i + 1];
      if (np == 0) {
        int tb = (i + 1) * 4;
#pragma unroll
        for (int u = 0; u < 4; u++) zn[u] = zbase[(size_t)(tb + u) * 256];
      }
    }
    float4 y;
    STEP1(cd.x, cx.x, cb0.x, cb1.x, cc0.x, cc1.x, y.x);
    STEP1(cd.y, cx.y, cb0.y, cb1.y, cc0.y, cc1.y, y.y);
    STEP1(cd.z, cx.z, cb0.z, cb1.z, cc0.z, cc1.z, y.z);
    STEP1(cd.w, cx.w, cb0.w, cb1.w, cc0.w, cc1.w, y.w);
    if (np == 0) {
      y.x *= silu_f(zc[0]);
      y.y *= silu_f(zc[1]);
      y.z *= silu_f(zc[2]);
      y.w *= silu_f(zc[3]);
      y4[i] = y;
#pragma unroll
      for (int u = 0; u < 4; u++) zc[u] = zn[u];
    }
    cd = nd; cx = nx; cb0 = nb0; cb1 = nb1; cc0 = nc0; cc1 = nc1;
  }
#undef STEP1
}

// ---------------------------------------------------------------------------
// k_out: H1 = LN1( H + Yf@opw_f.T + Yr@opw_r.T ). 32-row tiles, dbuf over
// 8 virtual k-tiles (dirp,k0). grid (33, 8), block 256.
// ---------------------------------------------------------------------------
__global__ __launch_bounds__(256) void k_out(
    const float* __restrict__ YT, const float* __restrict__ Hin,
    const float* __restrict__ opw,
    const float* __restrict__ n1w, const float* __restrict__ n1b,
    float* __restrict__ H1, int l) {
  int b = blockIdx.y;
  int t0 = blockIdx.x * 32;
  int tid = threadIdx.x;
  int tm = tid & 15, tt = tid >> 4;
  __shared__ float As[2][32][36];
  __shared__ float Ws[2][32][132];
  float acc[2][8] = {{0.f}};
  int krow = tid >> 3, t4 = tid & 7;

  float4 aN;
  float4 wN[4];
#define LOAD_OUT(KT)                                                          \
  {                                                                           \
    int dirp_ = (KT) >> 2;                                                    \
    int k0_ = ((KT) & 3) * 32;                                                \
    size_t rowbase_ = ((size_t)(dirp_ * BATCH + b) * 128 + k0_ + krow) * LP;  \
    if (dirp_ == 0) {                                                         \
      aN = *(const float4*)(YT + rowbase_ + t0 + t4 * 4);                     \
    } else {                                                                  \
      int tg_ = t0 + t4 * 4;                                                  \
      float tmp_[4];                                                          \
      _Pragma("unroll")                                                       \
      for (int u = 0; u < 4; u++) {                                           \
        int src_ = (L_SEQ - 1) - (tg_ + u);                                   \
        tmp_[u] = (src_ >= 0) ? YT[rowbase_ + src_] : 0.f;                    \
      }                                                                       \
      aN = make_float4(tmp_[0], tmp_[1], tmp_[2], tmp_[3]);                   \
    }                                                                         \
    const float* wsrc_ = opw + (size_t)(l * 2 + dirp_) * 128 * 128;           \
    _Pragma("unroll")                                                         \
    for (int i_ = 0; i_ < 4; i_++) {                                          \
      int e_ = tid + i_ * 256;                                                \
      int n_ = e_ >> 3, kk_ = e_ & 7;                                         \
      wN[i_] = *(const float4*)&wsrc_[(size_t)n_ * 128 + k0_ + kk_ * 4];      \
    }                                                                         \
  }
  LOAD_OUT(0);
  // A commit: rows = k (krow), cols = t (t4*4..)
  As[0][krow][t4 * 4 + 0] = aN.x;
  As[0][krow][t4 * 4 + 1] = aN.y;
  As[0][krow][t4 * 4 + 2] = aN.z;
  As[0][krow][t4 * 4 + 3] = aN.w;
  COMMIT_W(Ws[0], wN);
#pragma unroll 1
  for (int kt = 0; kt < 8; kt++) {
    __syncthreads();
    int cur = kt & 1;
    bool more = (kt + 1) < 8;
    if (more) LOAD_OUT(kt + 1);
    GEMM_INNER(As[cur], Ws[cur], acc);
    if (more) {
      int nb = (kt + 1) & 1;
      As[nb][krow][t4 * 4 + 0] = aN.x;
      As[nb][krow][t4 * 4 + 1] = aN.y;
      As[nb][krow][t4 * 4 + 2] = aN.z;
      As[nb][krow][t4 * 4 + 3] = aN.w;
      COMMIT_W(Ws[nb], wN);
    }
  }
#undef LOAD_OUT
  const float* nw = n1w + l * 128;
  const float* nb2 = n1b + l * 128;
#pragma unroll
  for (int r = 0; r < 2; r++) {
    int t = t0 + tt * 2 + r;
    float4 h0 = make_float4(0.f, 0.f, 0.f, 0.f);
    float4 h1 = make_float4(0.f, 0.f, 0.f, 0.f);
    if (t < L_SEQ) {
      const float* hp = &Hin[((size_t)b * L_SEQ + t) * 128];
      h0 = *(const float4*)&hp[tm * 4];
      h1 = *(const float4*)&hp[64 + tm * 4];
    }
    float v[8];
    v[0] = acc[r][0] + h0.x; v[1] = acc[r][1] + h0.y;
    v[2] = acc[r][2] + h0.z; v[3] = acc[r][3] + h0.w;
    v[4] = acc[r][4] + h1.x; v[5] = acc[r][5] + h1.y;
    v[6] = acc[r][6] + h1.z; v[7] = acc[r][7] + h1.w;
    float s1 = 0.f, s2 = 0.f;
#pragma unroll
    for (int jq = 0; jq < 8; jq++) { s1 += v[jq]; s2 += v[jq] * v[jq]; }
#pragma unroll
    for (int msk = 1; msk < 16; msk <<= 1) {
      s1 += __shfl_xor(s1, msk);
      s2 += __shfl_xor(s2, msk);
    }
    float mean = s1 * (1.f / 128.f);
    float rstd = rsqrtf(s2 * (1.f / 128.f) - mean * mean + 1e-5f);
    if (t < L_SEQ) {
      float* dst = &H1[((size_t)b * L_SEQ + t) * 128];
      float4 o0 = make_float4((v[0] - mean) * rstd * nw[tm * 4 + 0] + nb2[tm * 4 + 0],
                              (v[1] - mean) * rstd * nw[tm * 4 + 1] + nb2[tm * 4 + 1],
                              (v[2] - mean) * rstd * nw[tm * 4 + 2] + nb2[tm * 4 + 2],
                              (v[3] - mean) * rstd * nw[tm * 4 + 3] + nb2[tm * 4 + 3]);
      float4 o1 = make_float4((v[4] - mean) * rstd * nw[64 + tm * 4 + 0] + nb2[64 + tm * 4 + 0],
                              (v[5] - mean) * rstd * nw[64 + tm * 4 + 1] + nb2[64 + tm * 4 + 1],
                              (v[6] - mean) * rstd * nw[64 + tm * 4 + 2] + nb2[64 + tm * 4 + 2],
                              (v[7] - mean) * rstd * nw[64 + tm * 4 + 3] + nb2[64 + tm * 4 + 3]);
      *(float4*)&dst[tm * 4] = o0;
      *(float4*)&dst[64 + tm * 4] = o1;
    }
  }
}

// ---------------------------------------------------------------------------
// k_ffn: H = LN2( h1 + relu(h1@w1.T+b1)@w2.T + b2 ). 32-row tiles, dbuf.
// grid (33, 8), block 256.
// ---------------------------------------------------------------------------
__global__ __launch_bounds__(256) void k_ffn(
    const float* __restrict__ H1, const float* __restrict__ w1,
    const float* __restrict__ b1, const float* __restrict__ w2,
    const float* __restrict__ b2, const float* __restrict__ n2w,
    const float* __restrict__ n2b, float* __restrict__ Hout, int l) {
  int b = blockIdx.y;
  int t0 = blockIdx.x * 32;
  int tid = threadIdx.x;
  int tm = tid & 15, tt = tid >> 4;
  __shared__ float As[2][32][36];
  __shared__ float Ws[2][32][132];
  __shared__ float Ut[128][36];
  float acc[2][8] = {{0.f}};
  const float* w1b = w1 + (size_t)l * 128 * 128;
  int row = tid >> 3, k4 = tid & 7;
  int t = t0 + row;
  bool tin = (t < L_SEQ);

  float4 aN;
  float4 wN[4];
#define LOAD_FFN_A(K0)                                                        \
  {                                                                           \
    aN = make_float4(0.f, 0.f, 0.f, 0.f);                                     \
    if (tin)                                                                  \
      aN = *(const float4*)&H1[((size_t)b * L_SEQ + t) * 128 + (K0) + k4 * 4];\
  }
#define LOAD_FFN_W(WB, K0)                                                    \
  _Pragma("unroll")                                                           \
  for (int i_ = 0; i_ < 4; i_++) {                                            \
    int e_ = tid + i_ * 256;                                                  \
    int n_ = e_ >> 3, kk_ = e_ & 7;                                           \
    wN[i_] = *(const float4*)&(WB)[(size_t)n_ * 128 + (K0) + kk_ * 4];        \
  }
  LOAD_FFN_A(0);
  LOAD_FFN_W(w1b, 0);
  COMMIT_A(As[0], aN);
  COMMIT_W(Ws[0], wN);
#pragma unroll 1
  for (int kt = 0; kt < 4; kt++) {
    __syncthreads();
    int cur = kt & 1;
    bool more = (kt + 1) < 4;
    if (more) {
      int k0 = (kt + 1) * 32;
      LOAD_FFN_A(k0);
      LOAD_FFN_W(w1b, k0);
    }
    GEMM_INNER(As[cur], Ws[cur], acc);
    if (more) {
      int nb = (kt + 1) & 1;
      COMMIT_A(As[nb], aN);
      COMMIT_W(Ws[nb], wN);
    }
  }
  __syncthreads();   // all reads of As/Ws done before Ut write reuses nothing; Ut is separate
#pragma unroll
  for (int jq = 0; jq < 4; jq++) {
    int f0 = tm * 4 + jq;
    int f1 = 64 + tm * 4 + jq;
    float2 u0 = make_float2(fmaxf(acc[0][jq] + b1[l * 128 + f0], 0.f),
                            fmaxf(acc[1][jq] + b1[l * 128 + f0], 0.f));
    float2 u1 = make_float2(fmaxf(acc[0][4 + jq] + b1[l * 128 + f1], 0.f),
                            fmaxf(acc[1][4 + jq] + b1[l * 128 + f1], 0.f));
    *(float2*)&Ut[f0][tt * 2] = u0;
    *(float2*)&Ut[f1][tt * 2] = u1;
    acc[0][jq] = 0.f; acc[1][jq] = 0.f;
    acc[0][4 + jq] = 0.f; acc[1][4 + jq] = 0.f;
  }
  const float* w2b = w2 + (size_t)l * 128 * 128;
  LOAD_FFN_W(w2b, 0);
  COMMIT_W(Ws[0], wN);
#pragma unroll 1
  for (int kt = 0; kt < 4; kt++) {
    __syncthreads();
    int cur = kt & 1;
    bool more = (kt + 1) < 4;
    if (more) LOAD_FFN_W(w2b, (kt + 1) * 32);
    {
      const float(*W_)[132] = Ws[cur];
      int k0 = kt * 32;
#pragma unroll
      for (int k = 0; k < 32; k++) {
        float2 a = *(const float2*)&Ut[k0 + k][tt * 2];
        float4 w0 = *(const float4*)&W_[k][tm * 4];
        float4 w1v = *(const float4*)&W_[k][64 + tm * 4];
        acc[0][0] = fmaf(a.x, w0.x, acc[0][0]);
        acc[0][1] = fmaf(a.x, w0.y, acc[0][1]);
        acc[0][2] = fmaf(a.x, w0.z, acc[0][2]);
        acc[0][3] = fmaf(a.x, w0.w, acc[0][3]);
        acc[0][4] = fmaf(a.x, w1v.x, acc[0][4]);
        acc[0][5] = fmaf(a.x, w1v.y, acc[0][5]);
        acc[0][6] = fmaf(a.x, w1v.z, acc[0][6]);
        acc[0][7] = fmaf(a.x, w1v.w, acc[0][7]);
        acc[1][0] = fmaf(a.y, w0.x, acc[1][0]);
        acc[1][1] = fmaf(a.y, w0.y, acc[1][1]);
        acc[1][2] = fmaf(a.y, w0.z, acc[1][2]);
        acc[1][3] = fmaf(a.y, w0.w, acc[1][3]);
        acc[1][4] = fmaf(a.y, w1v.x, acc[1][4]);
        acc[1][5] = fmaf(a.y, w1v.y, acc[1][5]);
        acc[1][6] = fmaf(a.y, w1v.z, acc[1][6]);
        acc[1][7] = fmaf(a.y, w1v.w, acc[1][7]);
      }
    }
    if (more) {
      int nb = (kt + 1) & 1;
      COMMIT_W(Ws[nb], wN);
    }
  }
#undef LOAD_FFN_A
#undef LOAD_FFN_W
  const float* nw = n2w + l * 128;
  const float* nb2 = n2b + l * 128;
#pragma unroll
  for (int r = 0; r < 2; r++) {
    int to = t0 + tt * 2 + r;
    float4 h0 = make_float4(0.f, 0.f, 0.f, 0.f);
    float4 h1 = make_float4(0.f, 0.f, 0.f, 0.f);
    if (to < L_SEQ) {
      const float* hp = &H1[((size_t)b * L_SEQ + to) * 128];
      h0 = *(const float4*)&hp[tm * 4];
      h1 = *(const float4*)&hp[64 + tm * 4];
    }
    float v[8];
    v[0] = acc[r][0] + b2[l * 128 + tm * 4 + 0] + h0.x;
    v[1] = acc[r][1] + b2[l * 128 + tm * 4 + 1] + h0.y;
    v[2] = acc[r][2] + b2[l * 128 + tm * 4 + 2] + h0.z;
    v[3] = acc[r][3] + b2[l * 128 + tm * 4 + 3] + h0.w;
    v[4] = acc[r][4] + b2[l * 128 + 64 + tm * 4 + 0] + h1.x;
    v[5] = acc[r][5] + b2[l * 128 + 64 + tm * 4 + 1] + h1.y;
    v[6] = acc[r][6] + b2[l * 128 + 64 + tm * 4 + 2] + h1.z;
    v[7] = acc[r][7] + b2[l * 128 + 64 + tm * 4 + 3] + h1.w;
    float s1 = 0.f, s2 = 0.f;
#pragma unroll
    for (int jq = 0; jq < 8; jq++) { s1 += v[jq]; s2 += v[jq] * v[jq]; }
#pragma unroll
    for (int msk = 1; msk < 16; msk <<= 1) {
      s1 += __shfl_xor(s1, msk);
      s2 += __shfl_xor(s2, msk);
    }
    float mean = s1 * (1.f / 128.f);
    float rstd = rsqrtf(s2 * (1.f / 128.f) - mean * mean + 1e-5f);
    if (to < L_SEQ) {
      float* dst = &Hout[((size_t)b * L_SEQ + to) * 128];
      float4 o0 = make_float4((v[0] - mean) * rstd * nw[tm * 4 + 0] + nb2[tm * 4 + 0],
                              (v[1] - mean) * rstd * nw[tm * 4 + 1] + nb2[tm * 4 + 1],
                              (v[2] - mean) * rstd * nw[tm * 4 + 2] + nb2[tm * 4 + 2],
                              (v[3] - mean) * rstd * nw[tm * 4 + 3] + nb2[tm * 4 + 3]);
      float4 o1 = make_float4((v[4] - mean) * rstd * nw[64 + tm * 4 + 0] + nb2[64 + tm * 4 + 0],
                              (v[5] - mean) * rstd * nw[64 + tm * 4 + 1] + nb2[64 + tm * 4 + 1],
                              (v[6] - mean) * rstd * nw[64 + tm * 4 + 2] + nb2[64 + tm * 4 + 2],
                              (v[7] - mean) * rstd * nw[64 + tm * 4 + 3] + nb2[64 + tm * 4 + 3]);
      *(float4*)&dst[tm * 4] = o0;
      *(float4*)&dst[64 + tm * 4] = o1;
    }
  }
}

// ---------------------------------------------------------------------------
// k_final  (round-3, proven)
// ---------------------------------------------------------------------------
__global__ __launch_bounds__(256) void k_final(
    const float* __restrict__ Hsrc, const float* __restrict__ fw,
    const float* __restrict__ fb, const float* __restrict__ pw,
    const float* __restrict__ pb, float* __restrict__ out) {
  int b = blockIdx.y;
  int v0 = blockIdx.x * 16;
  int tid = threadIdx.x;
  __shared__ float At[128][17];
  __shared__ float Ws[32][97];
  __shared__ float Os[96][17];
  for (int i = 0; i < 8; i++) {
    int e = tid + i * 256;
    int k = e & 127, tl = e >> 7;
    At[k][tl] = Hsrc[((size_t)b * L_SEQ + v0 + tl) * 128 + k];
  }
  __syncthreads();
  {
    int g = tid & 15, tl = tid >> 4;
    float s1 = 0.f, s2 = 0.f;
#pragma unroll
    for (int kk = 0; kk < 8; kk++) {
      float v = At[g * 8 + kk][tl];
      s1 += v;
      s2 += v * v;
    }
#pragma unroll
    for (int msk = 1; msk < 16; msk <<= 1) {
      s1 += __shfl_xor(s1, msk);
      s2 += __shfl_xor(s2, msk);
    }
    float mean = s1 * (1.f / 128.f);
    float rstd = rsqrtf(s2 * (1.f / 128.f) - mean * mean + 1e-5f);
#pragma unroll
    for (int kk = 0; kk < 8; kk++) {
      int k = g * 8 + kk;
      At[k][tl] = (At[k][tl] - mean) * rstd * fw[k] + fb[k];
    }
  }
  __syncthreads();
  int tm = tid & 15, tt = tid >> 4;
  float acc[6] = {0.f};
  for (int k0 = 0; k0 < 128; k0 += 32) {
    for (int i = 0; i < 12; i++) {
      int e = tid + i * 256;
      int ki = e & 31, p = e >> 5;
      Ws[ki][p] = pw[(size_t)p * 128 + k0 + ki];
    }
    __syncthreads();
    for (int ki = 0; ki < 32; ki++) {
      float a = At[k0 + ki][tt];
#pragma unroll
      for (int jq = 0; jq < 6; jq++)
        acc[jq] = fmaf(a, Ws[ki][tm + jq * 16], acc[jq]);
    }
    __syncthreads();
  }
#pragma unroll
  for (int jq = 0; jq < 6; jq++) {
    int p = tm + jq * 16;
    Os[p][tt] = acc[jq] + pb[p];
  }
  __syncthreads();
  for (int i = 0; i < 6; i++) {
    int e = tid + i * 256;
    int vi = e & 15, p = e >> 4;
    out[((size_t)b * 96 + p) * 1024 + v0 + vi] = Os[p][vi];
  }
}

// ---------------------------------------------------------------------------
extern "C" void kernel_launch(void* const* d_in, const int* in_sizes, int n_in,
                              void* d_out, int out_size, void* d_ws, size_t ws_size,
                              hipStream_t stream) {
  (void)in_sizes; (void)n_in; (void)out_size; (void)ws_size;
  const float* x_enc  = (const float*)d_in[0];
  const float* x_mark = (const float*)d_in[1];
  const float* emb_w  = (const float*)d_in[4];
  const float* emb_b  = (const float*)d_in[5];
  const float* ipw    = (const float*)d_in[6];
  const float* cw     = (const float*)d_in[7];
  const float* cb     = (const float*)d_in[8];
  const float* xpw    = (const float*)d_in[9];
  const float* dpw    = (const float*)d_in[10];
  const float* dpb    = (const float*)d_in[11];
  const float* A_log  = (const float*)d_in[12];
  const float* Dpar   = (const float*)d_in[13];
  const float* opw    = (const float*)d_in[14];
  const float* n1w    = (const float*)d_in[15];
  const float* n1b    = (const float*)d_in[16];
  const float* n2w    = (const float*)d_in[17];
  const float* n2b    = (const float*)d_in[18];
  const float* fw1    = (const float*)d_in[19];
  const float* fb1    = (const float*)d_in[20];
  const float* fw2    = (const float*)d_in[21];
  const float* fb2    = (const float*)d_in[22];
  const float* fnw    = (const float*)d_in[23];
  const float* fnb    = (const float*)d_in[24];
  const float* pw     = (const float*)d_in[25];
  const float* pb     = (const float*)d_in[26];

  float* ws   = (float*)d_ws;
  float* H    = ws + OFF_H;
  float* H1   = ws + OFF_H1;
  float* XZ   = ws + OFF_XZ;
  float* XCT  = ws + OFF_XCT;
  float* DLT  = ws + OFF_DLT;
  float* BmT  = ws + OFF_BMT;
  float* CmT  = ws + OFF_CMT;
  float* YT   = ws + OFF_YT;
  float* sumH = ws + OFF_H1;             // overlay: H1 unused during scan
  float* sumP = ws + OFF_H1 + SZ_SUM;

  hipMemsetAsync(H, 0, SZ_H * sizeof(float), stream);
  k_embed<<<dim3(33, 8, 4), 256, 0, stream>>>(x_enc, x_mark, emb_w, emb_b, H);
  for (int l = 0; l < 2; l++) {
    k_xz<<<dim3(33, 8, 4), 256, 0, stream>>>(H, ipw, XZ, l);
    k_mid<<<dim3(34, 8, 2), 256, 0, stream>>>(XZ, cw, cb, xpw, dpw, dpb,
                                              XCT, DLT, BmT, CmT, l);
    k_scan1<<<dim3(16, 8, 32), 64, 0, stream>>>(DLT, XCT, BmT, A_log,
                                                sumH, sumP, l);
    k_scan2<<<dim3(16, 8, 32), 64, 0, stream>>>(DLT, XCT, BmT, CmT, XZ,
                                                A_log, Dpar, sumH, sumP, YT, l);
    k_out<<<dim3(33, 8), 256, 0, stream>>>(YT, H, opw, n1w, n1b, H1, l);
    k_ffn<<<dim3(33, 8), 256, 0, stream>>>(H1, fw1, fb1, fw2, fb2, n2w, n2b, H, l);
  }
  k_final<<<dim3(64, 8), 256, 0, stream>>>(H, fnw, fnb, pw, pb, (float*)d_out);
}

// Round 7
// 519.418 us; speedup vs baseline: 1.2022x; 1.2022x over previous
//
#include <hip/hip_runtime.h>
#include <math.h>

// ---------------------------------------------------------------------------
// Bidirectional Mamba encoder, fp32, round 7.
// Reverts round-6 dbuf/atomics. One change: GEMM fragment shape 4x8 per
// thread (1.33 flop/LDS-byte vs 0.8 -> LDS-BW ceiling 67% VALU, 32-FMA ILP).
// Block = 128 threads (2 waves), tile 32 rows x 128 cols, BK=32, plain
// stage->barrier->compute->barrier k-loop.
// k_mid / k_scan1 / k_scan2 / k_final: round-5, proven.
// ---------------------------------------------------------------------------

#define L_SEQ 1031
#define LP    1088          // 16 chunks x 68
#define TC    68
#define NCH   16
#define BATCH 8
#define NVAR  1024
#define SEQQ  512
#define TFEAT 7

#define SZ_H    ((size_t)BATCH * L_SEQ * 128)
#define SZ_XZ   ((size_t)2 * BATCH * L_SEQ * 256)
#define SZ_DT   ((size_t)2 * BATCH * 128 * LP)
#define SZ_BC   ((size_t)2 * BATCH * 16 * LP)
#define OFF_H    ((size_t)0)
#define OFF_H1   (OFF_H + SZ_H)
#define OFF_XZ   (OFF_H1 + SZ_H)
#define OFF_XCT  (OFF_XZ + SZ_XZ)
#define OFF_DLT  (OFF_XCT + SZ_DT)
#define OFF_BMT  (OFF_DLT + SZ_DT)
#define OFF_CMT  (OFF_BMT + SZ_BC)
#define OFF_YT   (OFF_CMT + SZ_BC)
#define SZ_SUM  ((size_t)2 * BATCH * NCH * 128 * 16)   // 524,288 floats

__device__ __forceinline__ float silu_f(float x) {
  return x / (1.f + __expf(-x));
}
__device__ __forceinline__ float softplus_f(float x) {
  return (x > 20.f) ? x : log1pf(__expf(x));
}
__device__ __forceinline__ float red8(float x) {
  x += __int_as_float(__builtin_amdgcn_update_dpp(
      0, __float_as_int(x), 0xB1, 0xF, 0xF, true));   // quad_perm [1,0,3,2]
  x += __int_as_float(__builtin_amdgcn_update_dpp(
      0, __float_as_int(x), 0x4E, 0xF, 0xF, true));   // quad_perm [2,3,0,1]
  x += __int_as_float(__builtin_amdgcn_update_dpp(
      0, __float_as_int(x), 0x141, 0xF, 0xF, true));  // row_half_mirror
  return x;
}

// 4 rows x (4+4) cols per thread. tm = tid&15 (cols tm*4, 64+tm*4),
// tr = tid>>4 (0..7, rows tr*4..tr*4+3). 64 B LDS per 64 flop per k-step.
#define GEMM_INNER48(AS, WS, ACC)                                   \
  _Pragma("unroll")                                                 \
  for (int k = 0; k < 32; k++) {                                    \
    float4 a = *(const float4*)&AS[k][tr * 4];                      \
    float4 w0 = *(const float4*)&WS[k][tm * 4];                     \
    float4 w1 = *(const float4*)&WS[k][64 + tm * 4];                \
    float av[4] = {a.x, a.y, a.z, a.w};                             \
    float wv[8] = {w0.x, w0.y, w0.z, w0.w, w1.x, w1.y, w1.z, w1.w}; \
    _Pragma("unroll")                                               \
    for (int r_ = 0; r_ < 4; r_++)                                  \
      _Pragma("unroll")                                             \
      for (int c_ = 0; c_ < 8; c_++)                                \
        ACC[r_][c_] = fmaf(av[r_], wv[c_], ACC[r_][c_]);            \
  }

// W stage: 128 n x 32 k, 8 float4 per thread (128-thread block)
#define STAGE_W(WS, SRC, LDK, K0)                                   \
  _Pragma("unroll")                                                 \
  for (int i_ = 0; i_ < 8; i_++) {                                  \
    int e_ = tid + i_ * 128;                                        \
    int n_ = e_ >> 3, k4_ = e_ & 7;                                 \
    float4 w_ = *(const float4*)&(SRC)[(size_t)n_ * (LDK) + (K0) + k4_ * 4]; \
    WS[k4_ * 4 + 0][n_] = w_.x;                                     \
    WS[k4_ * 4 + 1][n_] = w_.y;                                     \
    WS[k4_ * 4 + 2][n_] = w_.z;                                     \
    WS[k4_ * 4 + 3][n_] = w_.w;                                     \
  }

// ---------------------------------------------------------------------------
// k_embed: H[b,v,:] = token(b,v,:) @ emb_w.T + emb_b. K=512 over s.
// grid (33, 8), block 128. Tile 32 v x 128 m.
// ---------------------------------------------------------------------------
__global__ __launch_bounds__(128) void k_embed(
    const float* __restrict__ x_enc, const float* __restrict__ x_mark,
    const float* __restrict__ emb_w, const float* __restrict__ emb_b,
    float* __restrict__ H) {
  int b = blockIdx.y;
  int v0 = blockIdx.x * 32;
  int tid = threadIdx.x;
  int tm = tid & 15, tr = tid >> 4;
  __shared__ float As[32][36];    // [s][v]
  __shared__ float Ws[32][132];   // [s][m]
  float acc[4][8] = {{0.f}};
  for (int s0 = 0; s0 < SEQQ; s0 += 32) {
    // A: 32 v x 32 s; 2 float4 (along v) per thread
#pragma unroll
    for (int i = 0; i < 2; i++) {
      int e = tid + i * 128;
      int vq = e & 7, si = e >> 3;   // vq: 8 groups of 4 v; si: 32 s
      int vg = v0 + vq * 4;
      int s = s0 + si;
      if (vg + 3 < NVAR) {
        float4 x = *(const float4*)&x_enc[((size_t)b * SEQQ + s) * NVAR + vg];
        if (x.x == -9999.f) x.x = -1.f;
        if (x.y == -9999.f) x.y = -1.f;
        if (x.z == -9999.f) x.z = -1.f;
        if (x.w == -9999.f) x.w = -1.f;
        As[si][vq * 4 + 0] = x.x;
        As[si][vq * 4 + 1] = x.y;
        As[si][vq * 4 + 2] = x.z;
        As[si][vq * 4 + 3] = x.w;
      } else {
#pragma unroll
        for (int u = 0; u < 4; u++) {
          int v = vg + u;
          float val = 0.f;
          if (v < L_SEQ)
            val = x_mark[((size_t)b * SEQQ + s) * TFEAT + (v - NVAR)];
          As[si][vq * 4 + u] = val;
        }
      }
    }
    STAGE_W(Ws, emb_w, SEQQ, s0);
    __syncthreads();
    GEMM_INNER48(As, Ws, acc);
    __syncthreads();
  }
#pragma unroll
  for (int r = 0; r < 4; r++) {
    int v = v0 + tr * 4 + r;
    if (v < L_SEQ) {
      float* dst = &H[((size_t)b * L_SEQ + v) * 128];
      float4 o0 = make_float4(acc[r][0] + emb_b[tm * 4 + 0],
                              acc[r][1] + emb_b[tm * 4 + 1],
                              acc[r][2] + emb_b[tm * 4 + 2],
                              acc[r][3] + emb_b[tm * 4 + 3]);
      float4 o1 = make_float4(acc[r][4] + emb_b[64 + tm * 4 + 0],
                              acc[r][5] + emb_b[64 + tm * 4 + 1],
                              acc[r][6] + emb_b[64 + tm * 4 + 2],
                              acc[r][7] + emb_b[64 + tm * 4 + 3]);
      *(float4*)&dst[tm * 4] = o0;
      *(float4*)&dst[64 + tm * 4] = o1;
    }
  }
}

// ---------------------------------------------------------------------------
// k_xz: XZ[dir,b,t,nh*128:+128] = h_dir(b,t,:) @ ipw[l,dir,nh].T. K=128.
// grid (33, 8, 4) z=(dir,nh), block 128. Tile 32 t x 128 n.
// ---------------------------------------------------------------------------
__global__ __launch_bounds__(128) void k_xz(
    const float* __restrict__ H, const float* __restrict__ ipw,
    float* __restrict__ XZ, int l) {
  int b = blockIdx.y;
  int dir = blockIdx.z >> 1, nh = blockIdx.z & 1;
  int t0 = blockIdx.x * 32;
  int tid = threadIdx.x;
  int tm = tid & 15, tr = tid >> 4;
  __shared__ float As[32][36];
  __shared__ float Ws[32][132];
  float acc[4][8] = {{0.f}};
  const float* wbase = ipw + (size_t)(l * 2 + dir) * 256 * 128 + (size_t)nh * 128 * 128;
  for (int k0 = 0; k0 < 128; k0 += 32) {
#pragma unroll
    for (int i = 0; i < 2; i++) {
      int e = tid + i * 128;
      int k4 = e & 7, row = e >> 3;
      int t = t0 + row;
      float4 hv = make_float4(0.f, 0.f, 0.f, 0.f);
      if (t < L_SEQ) {
        int st = dir ? (L_SEQ - 1 - t) : t;
        hv = *(const float4*)&H[((size_t)b * L_SEQ + st) * 128 + k0 + k4 * 4];
      }
      As[k4 * 4 + 0][row] = hv.x;
      As[k4 * 4 + 1][row] = hv.y;
      As[k4 * 4 + 2][row] = hv.z;
      As[k4 * 4 + 3][row] = hv.w;
    }
    STAGE_W(Ws, wbase, 128, k0);
    __syncthreads();
    GEMM_INNER48(As, Ws, acc);
    __syncthreads();
  }
#pragma unroll
  for (int r = 0; r < 4; r++) {
    int t = t0 + tr * 4 + r;
    if (t < L_SEQ) {
      float* dst = XZ + ((size_t)(dir * BATCH + b) * L_SEQ + t) * 256 + nh * 128;
      *(float4*)&dst[tm * 4] = *(float4*)&acc[r][0];
      *(float4*)&dst[64 + tm * 4] = *(float4*)&acc[r][4];
    }
  }
}

// ---------------------------------------------------------------------------
// k_mid  (round-5, proven; grid (34,8,2) covers LP=1088)
// ---------------------------------------------------------------------------
__global__ __launch_bounds__(256) void k_mid(
    const float* __restrict__ XZ,
    const float* __restrict__ conv_w, const float* __restrict__ conv_b,
    const float* __restrict__ xpw,
    const float* __restrict__ dpw, const float* __restrict__ dpb,
    float* __restrict__ XCT, float* __restrict__ DLT,
    float* __restrict__ BmT, float* __restrict__ CmT, int l) {
  int b = blockIdx.y, dir = blockIdx.z;
  int t0 = blockIdx.x * 32;
  int tid = threadIdx.x;
  int pg = l * 2 + dir;
  __shared__ float xcs[32][132];
  __shared__ float xpws[40][128];
  __shared__ float dbcs[40][36];
  const float* xz = XZ + (size_t)(dir * BATCH + b) * L_SEQ * 256;

  for (int i = 0; i < 20; i++) {
    int e = tid + i * 256;
    int k = e & 127, j = e >> 7;
    xpws[j][k] = xpw[((size_t)pg * 40 + j) * 128 + k];
  }
  for (int i = 0; i < 16; i++) {
    int e = tid + i * 256;
    int d = e & 127, tl = e >> 7;
    int t = t0 + tl;
    float v = 0.f;
    if (t < L_SEQ) {
      float x1 = xz[(size_t)t * 256 + d];
      float x0 = (t > 0) ? xz[(size_t)(t - 1) * 256 + d] : 0.f;
      float c0 = conv_w[((size_t)pg * 128 + d) * 2 + 0];
      float c1 = conv_w[((size_t)pg * 128 + d) * 2 + 1];
      v = silu_f(x0 * c0 + x1 * c1 + conv_b[(size_t)pg * 128 + d]);
    }
    xcs[tl][d] = v;
  }
  __syncthreads();
  {
    int tl = tid & 31, jg = tid >> 5;
    float acc[5] = {0.f};
    const float4* xrow = (const float4*)&xcs[tl][0];
    for (int kk = 0; kk < 32; kk++) {
      float4 a = xrow[kk];
#pragma unroll
      for (int jj = 0; jj < 5; jj++) {
        float4 w = ((const float4*)&xpws[jg * 5 + jj][0])[kk];
        acc[jj] = fmaf(a.x, w.x, acc[jj]);
        acc[jj] = fmaf(a.y, w.y, acc[jj]);
        acc[jj] = fmaf(a.z, w.z, acc[jj]);
        acc[jj] = fmaf(a.w, w.w, acc[jj]);
      }
    }
#pragma unroll
    for (int jj = 0; jj < 5; jj++) dbcs[jg * 5 + jj][tl] = acc[jj];
  }
  __syncthreads();
  for (int i = 0; i < 4; i++) {
    int e = tid + i * 256;
    int tl = e & 31, r = e >> 5;
    int n = r & 15, isC = r >> 4;
    int t = t0 + tl;
    if (t < LP) {
      float v = dbcs[8 + isC * 16 + n][tl];
      float* dst = isC ? CmT : BmT;
      dst[((size_t)(dir * BATCH + b) * 16 + n) * LP + t] = v;
    }
  }
  {
    int d = tid & 127, th = tid >> 7;
    float dw[8];
#pragma unroll
    for (int k = 0; k < 8; k++) dw[k] = dpw[((size_t)pg * 128 + d) * 8 + k];
    float dbv = dpb[(size_t)pg * 128 + d];
    size_t base = ((size_t)(dir * BATCH + b) * 128 + d) * LP;
    for (int tb = th * 16; tb < th * 16 + 16; tb += 4) {
      int t = t0 + tb;
      if (t < LP) {
        float dv[4], xv[4];
#pragma unroll
        for (int u = 0; u < 4; u++) {
          int tl = tb + u;
          float a = dbv;
#pragma unroll
          for (int k = 0; k < 8; k++) a = fmaf(dbcs[k][tl], dw[k], a);
          dv[u] = softplus_f(a);
          xv[u] = xcs[tl][d];
        }
        *(float4*)(DLT + base + t) = make_float4(dv[0], dv[1], dv[2], dv[3]);
        *(float4*)(XCT + base + t) = make_float4(xv[0], xv[1], xv[2], xv[3]);
      }
    }
  }
}

// ---------------------------------------------------------------------------
// k_scan1  (round-5, proven)
// ---------------------------------------------------------------------------
__global__ __launch_bounds__(64) void k_scan1(
    const float* __restrict__ DLT, const float* __restrict__ XCT,
    const float* __restrict__ BmT,
    const float* __restrict__ A_log,
    float* __restrict__ sumH, float* __restrict__ sumP, int l) {
  int z = blockIdx.z;
  int dir = z >> 4, j = z & 15;
  int b = blockIdx.y;
  int lane = threadIdx.x;
  int np = lane & 7, ds = lane >> 3;
  int d = blockIdx.x * 8 + ds;
  int pg = l * 2 + dir;
  int n0 = np * 2;
  float A0 = -__expf(A_log[((size_t)pg * 128 + d) * 16 + n0]);
  float A1 = -__expf(A_log[((size_t)pg * 128 + d) * 16 + n0 + 1]);
  size_t bd = ((size_t)(dir * BATCH + b) * 128 + d) * LP + (size_t)j * TC;
  size_t bn = ((size_t)(dir * BATCH + b) * 16 + n0) * LP + (size_t)j * TC;
  const float4* dl4 = (const float4*)(DLT + bd);
  const float4* xc4 = (const float4*)(XCT + bd);
  const float4* b04 = (const float4*)(BmT + bn);
  const float4* b14 = (const float4*)(BmT + bn + LP);
  float h0 = 0.f, h1 = 0.f, sdl = 0.f;
  const int NI = TC / 4;   // 17
  float4 cd = dl4[0], cx = xc4[0], cb0 = b04[0], cb1 = b14[0];
#define P1STEP(DL, XC, B0, B1)                       \
  {                                                  \
    float du_ = (DL) * (XC);                         \
    h0 = fmaf(__expf((DL) * A0), h0, du_ * (B0));    \
    h1 = fmaf(__expf((DL) * A1), h1, du_ * (B1));    \
  }
  for (int i = 0; i < NI; i++) {
    float4 nd = cd, nx = cx, nb0 = cb0, nb1 = cb1;
    if (i + 1 < NI) {
      nd = dl4[i + 1]; nx = xc4[i + 1];
      nb0 = b04[i + 1]; nb1 = b14[i + 1];
    }
    P1STEP(cd.x, cx.x, cb0.x, cb1.x);
    P1STEP(cd.y, cx.y, cb0.y, cb1.y);
    P1STEP(cd.z, cx.z, cb0.z, cb1.z);
    P1STEP(cd.w, cx.w, cb0.w, cb1.w);
    sdl += (cd.x + cd.y) + (cd.z + cd.w);
    cd = nd; cx = nx; cb0 = nb0; cb1 = nb1;
  }
#undef P1STEP
  size_t si = (((size_t)(dir * BATCH + b) * NCH + j) * 128 + d) * 16 + n0;
  *(float2*)&sumH[si] = make_float2(h0, h1);
  *(float2*)&sumP[si] = make_float2(__expf(A0 * sdl), __expf(A1 * sdl));
}

// ---------------------------------------------------------------------------
// k_scan2  (round-5, proven)
// ---------------------------------------------------------------------------
__global__ __launch_bounds__(64) void k_scan2(
    const float* __restrict__ DLT, const float* __restrict__ XCT,
    const float* __restrict__ BmT, const float* __restrict__ CmT,
    const float* __restrict__ XZ,
    const float* __restrict__ A_log, const float* __restrict__ Dpar,
    const float* __restrict__ sumH, const float* __restrict__ sumP,
    float* __restrict__ YT, int l) {
  int z = blockIdx.z;
  int dir = z >> 4, j = z & 15;
  int b = blockIdx.y;
  int lane = threadIdx.x;
  int np = lane & 7, ds = lane >> 3;
  int d = blockIdx.x * 8 + ds;
  int pg = l * 2 + dir;
  int n0 = np * 2;
  float A0 = -__expf(A_log[((size_t)pg * 128 + d) * 16 + n0]);
  float A1 = -__expf(A_log[((size_t)pg * 128 + d) * 16 + n0 + 1]);
  float Dv = Dpar[(size_t)pg * 128 + d];
  float h0 = 0.f, h1 = 0.f;
  {
    size_t sbase = ((size_t)(dir * BATCH + b) * NCH) * 2048 + (size_t)d * 16 + n0;
    for (int jj = 0; jj < j; jj++) {
      float2 hE = *(const float2*)&sumH[sbase + (size_t)jj * 2048];
      float2 Pp = *(const float2*)&sumP[sbase + (size_t)jj * 2048];
      h0 = fmaf(Pp.x, h0, hE.x);
      h1 = fmaf(Pp.y, h1, hE.y);
    }
  }
  size_t bd = ((size_t)(dir * BATCH + b) * 128 + d) * LP + (size_t)j * TC;
  size_t bn = ((size_t)(dir * BATCH + b) * 16 + n0) * LP + (size_t)j * TC;
  const float4* dl4 = (const float4*)(DLT + bd);
  const float4* xc4 = (const float4*)(XCT + bd);
  const float4* b04 = (const float4*)(BmT + bn);
  const float4* b14 = (const float4*)(BmT + bn + LP);
  const float4* c04 = (const float4*)(CmT + bn);
  const float4* c14 = (const float4*)(CmT + bn + LP);
  const float* zbase = XZ + (size_t)(dir * BATCH + b) * L_SEQ * 256 + 128 + d
                       + (size_t)j * TC * 256;
  float4* y4 = (float4*)(YT + bd);
  const int NI = TC / 4;   // 17
  float4 cd = dl4[0], cx = xc4[0], cb0 = b04[0], cb1 = b14[0];
  float4 cc0 = c04[0], cc1 = c14[0];
  float zc[4], zn[4];
  if (np == 0) {
#pragma unroll
    for (int u = 0; u < 4; u++) zc[u] = zbase[(size_t)u * 256];
  }
#define STEP1(DL, XC, B0, B1, C0, C1, YO)            \
  {                                                  \
    float du_ = (DL) * (XC);                         \
    h0 = fmaf(__expf((DL) * A0), h0, du_ * (B0));    \
    h1 = fmaf(__expf((DL) * A1), h1, du_ * (B1));    \
    float p_ = red8(fmaf(h1, (C1), h0 * (C0)));      \
    (YO) = fmaf(Dv, (XC), p_);                       \
  }
  for (int i = 0; i < NI; i++) {
    float4 nd = cd, nx = cx, nb0 = cb0, nb1 = cb1, nc0 = cc0, nc1 = cc1;
    if (i + 1 < NI) {
      nd = dl4[i + 1]; nx = xc4[i + 1];
      nb0 = b04[i + 1]; nb1 = b14[i + 1];
      nc0 = c04[i + 1]; nc1 = c14[i + 1];
      if (np == 0) {
        int tb = (i + 1) * 4;
#pragma unroll
        for (int u = 0; u < 4; u++) zn[u] = zbase[(size_t)(tb + u) * 256];
      }
    }
    float4 y;
    STEP1(cd.x, cx.x, cb0.x, cb1.x, cc0.x, cc1.x, y.x);
    STEP1(cd.y, cx.y, cb0.y, cb1.y, cc0.y, cc1.y, y.y);
    STEP1(cd.z, cx.z, cb0.z, cb1.z, cc0.z, cc1.z, y.z);
    STEP1(cd.w, cx.w, cb0.w, cb1.w, cc0.w, cc1.w, y.w);
    if (np == 0) {
      y.x *= silu_f(zc[0]);
      y.y *= silu_f(zc[1]);
      y.z *= silu_f(zc[2]);
      y.w *= silu_f(zc[3]);
      y4[i] = y;
#pragma unroll
      for (int u = 0; u < 4; u++) zc[u] = zn[u];
    }
    cd = nd; cx = nx; cb0 = nb0; cb1 = nb1; cc0 = nc0; cc1 = nc1;
  }
#undef STEP1
}

// ---------------------------------------------------------------------------
// k_out: H1 = LN1( H + Yf@opw_f.T + Yr@opw_r.T ). K = 256 virtual
// (2 dir x 4 k-tiles). grid (33, 8), block 128. Tile 32 t x 128 m.
// ---------------------------------------------------------------------------
__global__ __launch_bounds__(128) void k_out(
    const float* __restrict__ YT, const float* __restrict__ Hin,
    const float* __restrict__ opw,
    const float* __restrict__ n1w, const float* __restrict__ n1b,
    float* __restrict__ H1, int l) {
  int b = blockIdx.y;
  int t0 = blockIdx.x * 32;
  int tid = threadIdx.x;
  int tm = tid & 15, tr = tid >> 4;
  __shared__ float As[32][36];
  __shared__ float Ws[32][132];
  float acc[4][8] = {{0.f}};
  for (int kt = 0; kt < 8; kt++) {
    int dirp = kt >> 2;
    int k0 = (kt & 3) * 32;
    // A: 32 k(d) x 32 t; 2 per thread
#pragma unroll
    for (int i = 0; i < 2; i++) {
      int e = tid + i * 128;
      int t4 = e & 7, krow = e >> 3;
      size_t rowbase = ((size_t)(dirp * BATCH + b) * 128 + k0 + krow) * LP;
      if (dirp == 0) {
        float4 y = *(const float4*)(YT + rowbase + t0 + t4 * 4);
        As[krow][t4 * 4 + 0] = y.x;
        As[krow][t4 * 4 + 1] = y.y;
        As[krow][t4 * 4 + 2] = y.z;
        As[krow][t4 * 4 + 3] = y.w;
      } else {
        int tg = t0 + t4 * 4;
#pragma unroll
        for (int u = 0; u < 4; u++) {
          int src = (L_SEQ - 1) - (tg + u);
          As[krow][t4 * 4 + u] = (src >= 0) ? YT[rowbase + src] : 0.f;
        }
      }
    }
    const float* wsrc = opw + (size_t)(l * 2 + dirp) * 128 * 128;
    STAGE_W(Ws, wsrc, 128, k0);
    __syncthreads();
    GEMM_INNER48(As, Ws, acc);
    __syncthreads();
  }
  const float* nw = n1w + l * 128;
  const float* nb2 = n1b + l * 128;
#pragma unroll
  for (int r = 0; r < 4; r++) {
    int t = t0 + tr * 4 + r;
    float4 h0 = make_float4(0.f, 0.f, 0.f, 0.f);
    float4 h1 = make_float4(0.f, 0.f, 0.f, 0.f);
    if (t < L_SEQ) {
      const float* hp = &Hin[((size_t)b * L_SEQ + t) * 128];
      h0 = *(const float4*)&hp[tm * 4];
      h1 = *(const float4*)&hp[64 + tm * 4];
    }
    float v[8];
    v[0] = acc[r][0] + h0.x; v[1] = acc[r][1] + h0.y;
    v[2] = acc[r][2] + h0.z; v[3] = acc[r][3] + h0.w;
    v[4] = acc[r][4] + h1.x; v[5] = acc[r][5] + h1.y;
    v[6] = acc[r][6] + h1.z; v[7] = acc[r][7] + h1.w;
    float s1 = 0.f, s2 = 0.f;
#pragma unroll
    for (int jq = 0; jq < 8; jq++) { s1 += v[jq]; s2 += v[jq] * v[jq]; }
#pragma unroll
    for (int msk = 1; msk < 16; msk <<= 1) {
      s1 += __shfl_xor(s1, msk);
      s2 += __shfl_xor(s2, msk);
    }
    float mean = s1 * (1.f / 128.f);
    float rstd = rsqrtf(s2 * (1.f / 128.f) - mean * mean + 1e-5f);
    if (t < L_SEQ) {
      float* dst = &H1[((size_t)b * L_SEQ + t) * 128];
      float4 o0 = make_float4((v[0] - mean) * rstd * nw[tm * 4 + 0] + nb2[tm * 4 + 0],
                              (v[1] - mean) * rstd * nw[tm * 4 + 1] + nb2[tm * 4 + 1],
                              (v[2] - mean) * rstd * nw[tm * 4 + 2] + nb2[tm * 4 + 2],
                              (v[3] - mean) * rstd * nw[tm * 4 + 3] + nb2[tm * 4 + 3]);
      float4 o1 = make_float4((v[4] - mean) * rstd * nw[64 + tm * 4 + 0] + nb2[64 + tm * 4 + 0],
                              (v[5] - mean) * rstd * nw[64 + tm * 4 + 1] + nb2[64 + tm * 4 + 1],
                              (v[6] - mean) * rstd * nw[64 + tm * 4 + 2] + nb2[64 + tm * 4 + 2],
                              (v[7] - mean) * rstd * nw[64 + tm * 4 + 3] + nb2[64 + tm * 4 + 3]);
      *(float4*)&dst[tm * 4] = o0;
      *(float4*)&dst[64 + tm * 4] = o1;
    }
  }
}

// ---------------------------------------------------------------------------
// k_ffn: H = LN2( h1 + relu(h1@w1.T+b1)@w2.T + b2 ).
// grid (33, 8), block 128. Tile 32 t; mid activations in Ut[128][36].
// ---------------------------------------------------------------------------
__global__ __launch_bounds__(128) void k_ffn(
    const float* __restrict__ H1, const float* __restrict__ w1,
    const float* __restrict__ b1, const float* __restrict__ w2,
    const float* __restrict__ b2, const float* __restrict__ n2w,
    const float* __restrict__ n2b, float* __restrict__ Hout, int l) {
  int b = blockIdx.y;
  int t0 = blockIdx.x * 32;
  int tid = threadIdx.x;
  int tm = tid & 15, tr = tid >> 4;
  __shared__ float As[32][36];
  __shared__ float Ws[32][132];
  __shared__ float Ut[128][36];
  float acc[4][8] = {{0.f}};
  const float* w1b = w1 + (size_t)l * 128 * 128;
  for (int k0 = 0; k0 < 128; k0 += 32) {
#pragma unroll
    for (int i = 0; i < 2; i++) {
      int e = tid + i * 128;
      int k4 = e & 7, row = e >> 3;
      int t = t0 + row;
      float4 hv = make_float4(0.f, 0.f, 0.f, 0.f);
      if (t < L_SEQ)
        hv = *(const float4*)&H1[((size_t)b * L_SEQ + t) * 128 + k0 + k4 * 4];
      As[k4 * 4 + 0][row] = hv.x;
      As[k4 * 4 + 1][row] = hv.y;
      As[k4 * 4 + 2][row] = hv.z;
      As[k4 * 4 + 3][row] = hv.w;
    }
    STAGE_W(Ws, w1b, 128, k0);
    __syncthreads();
    GEMM_INNER48(As, Ws, acc);
    __syncthreads();
  }
  // mid: relu(+b1) -> Ut[f][t]
#pragma unroll
  for (int jq = 0; jq < 4; jq++) {
    int f0 = tm * 4 + jq;
    int f1 = 64 + tm * 4 + jq;
    float b0 = b1[l * 128 + f0];
    float b1v = b1[l * 128 + f1];
    float4 u0 = make_float4(fmaxf(acc[0][jq] + b0, 0.f),
                            fmaxf(acc[1][jq] + b0, 0.f),
                            fmaxf(acc[2][jq] + b0, 0.f),
                            fmaxf(acc[3][jq] + b0, 0.f));
    float4 u1 = make_float4(fmaxf(acc[0][4 + jq] + b1v, 0.f),
                            fmaxf(acc[1][4 + jq] + b1v, 0.f),
                            fmaxf(acc[2][4 + jq] + b1v, 0.f),
                            fmaxf(acc[3][4 + jq] + b1v, 0.f));
    *(float4*)&Ut[f0][tr * 4] = u0;
    *(float4*)&Ut[f1][tr * 4] = u1;
#pragma unroll
    for (int r = 0; r < 4; r++) {
      acc[r][jq] = 0.f;
      acc[r][4 + jq] = 0.f;
    }
  }
  __syncthreads();
  const float* w2b = w2 + (size_t)l * 128 * 128;
  for (int k0 = 0; k0 < 128; k0 += 32) {
    STAGE_W(Ws, w2b, 128, k0);
    __syncthreads();
#pragma unroll
    for (int k = 0; k < 32; k++) {
      float4 a = *(const float4*)&Ut[k0 + k][tr * 4];
      float4 w0 = *(const float4*)&Ws[k][tm * 4];
      float4 w1v = *(const float4*)&Ws[k][64 + tm * 4];
      float av[4] = {a.x, a.y, a.z, a.w};
      float wv[8] = {w0.x, w0.y, w0.z, w0.w, w1v.x, w1v.y, w1v.z, w1v.w};
#pragma unroll
      for (int r_ = 0; r_ < 4; r_++)
#pragma unroll
        for (int c_ = 0; c_ < 8; c_++)
          acc[r_][c_] = fmaf(av[r_], wv[c_], acc[r_][c_]);
    }
    __syncthreads();
  }
  const float* nw = n2w + l * 128;
  const float* nb2 = n2b + l * 128;
#pragma unroll
  for (int r = 0; r < 4; r++) {
    int t = t0 + tr * 4 + r;
    float4 h0 = make_float4(0.f, 0.f, 0.f, 0.f);
    float4 h1 = make_float4(0.f, 0.f, 0.f, 0.f);
    if (t < L_SEQ) {
      const float* hp = &H1[((size_t)b * L_SEQ + t) * 128];
      h0 = *(const float4*)&hp[tm * 4];
      h1 = *(const float4*)&hp[64 + tm * 4];
    }
    float v[8];
    v[0] = acc[r][0] + b2[l * 128 + tm * 4 + 0] + h0.x;
    v[1] = acc[r][1] + b2[l * 128 + tm * 4 + 1] + h0.y;
    v[2] = acc[r][2] + b2[l * 128 + tm * 4 + 2] + h0.z;
    v[3] = acc[r][3] + b2[l * 128 + tm * 4 + 3] + h0.w;
    v[4] = acc[r][4] + b2[l * 128 + 64 + tm * 4 + 0] + h1.x;
    v[5] = acc[r][5] + b2[l * 128 + 64 + tm * 4 + 1] + h1.y;
    v[6] = acc[r][6] + b2[l * 128 + 64 + tm * 4 + 2] + h1.z;
    v[7] = acc[r][7] + b2[l * 128 + 64 + tm * 4 + 3] + h1.w;
    float s1 = 0.f, s2 = 0.f;
#pragma unroll
    for (int jq = 0; jq < 8; jq++) { s1 += v[jq]; s2 += v[jq] * v[jq]; }
#pragma unroll
    for (int msk = 1; msk < 16; msk <<= 1) {
      s1 += __shfl_xor(s1, msk);
      s2 += __shfl_xor(s2, msk);
    }
    float mean = s1 * (1.f / 128.f);
    float rstd = rsqrtf(s2 * (1.f / 128.f) - mean * mean + 1e-5f);
    if (t < L_SEQ) {
      float* dst = &Hout[((size_t)b * L_SEQ + t) * 128];
      float4 o0 = make_float4((v[0] - mean) * rstd * nw[tm * 4 + 0] + nb2[tm * 4 + 0],
                              (v[1] - mean) * rstd * nw[tm * 4 + 1] + nb2[tm * 4 + 1],
                              (v[2] - mean) * rstd * nw[tm * 4 + 2] + nb2[tm * 4 + 2],
                              (v[3] - mean) * rstd * nw[tm * 4 + 3] + nb2[tm * 4 + 3]);
      float4 o1 = make_float4((v[4] - mean) * rstd * nw[64 + tm * 4 + 0] + nb2[64 + tm * 4 + 0],
                              (v[5] - mean) * rstd * nw[64 + tm * 4 + 1] + nb2[64 + tm * 4 + 1],
                              (v[6] - mean) * rstd * nw[64 + tm * 4 + 2] + nb2[64 + tm * 4 + 2],
                              (v[7] - mean) * rstd * nw[64 + tm * 4 + 3] + nb2[64 + tm * 4 + 3]);
      *(float4*)&dst[tm * 4] = o0;
      *(float4*)&dst[64 + tm * 4] = o1;
    }
  }
}

// ---------------------------------------------------------------------------
// k_final  (round-3, proven)
// ---------------------------------------------------------------------------
__global__ __launch_bounds__(256) void k_final(
    const float* __restrict__ Hsrc, const float* __restrict__ fw,
    const float* __restrict__ fb, const float* __restrict__ pw,
    const float* __restrict__ pb, float* __restrict__ out) {
  int b = blockIdx.y;
  int v0 = blockIdx.x * 16;
  int tid = threadIdx.x;
  __shared__ float At[128][17];
  __shared__ float Ws[32][97];
  __shared__ float Os[96][17];
  for (int i = 0; i < 8; i++) {
    int e = tid + i * 256;
    int k = e & 127, tl = e >> 7;
    At[k][tl] = Hsrc[((size_t)b * L_SEQ + v0 + tl) * 128 + k];
  }
  __syncthreads();
  {
    int g = tid & 15, tl = tid >> 4;
    float s1 = 0.f, s2 = 0.f;
#pragma unroll
    for (int kk = 0; kk < 8; kk++) {
      float v = At[g * 8 + kk][tl];
      s1 += v;
      s2 += v * v;
    }
#pragma unroll
    for (int msk = 1; msk < 16; msk <<= 1) {
      s1 += __shfl_xor(s1, msk);
      s2 += __shfl_xor(s2, msk);
    }
    float mean = s1 * (1.f / 128.f);
    float rstd = rsqrtf(s2 * (1.f / 128.f) - mean * mean + 1e-5f);
#pragma unroll
    for (int kk = 0; kk < 8; kk++) {
      int k = g * 8 + kk;
      At[k][tl] = (At[k][tl] - mean) * rstd * fw[k] + fb[k];
    }
  }
  __syncthreads();
  int tm = tid & 15, tt = tid >> 4;
  float acc[6] = {0.f};
  for (int k0 = 0; k0 < 128; k0 += 32) {
    for (int i = 0; i < 12; i++) {
      int e = tid + i * 256;
      int ki = e & 31, p = e >> 5;
      Ws[ki][p] = pw[(size_t)p * 128 + k0 + ki];
    }
    __syncthreads();
    for (int ki = 0; ki < 32; ki++) {
      float a = At[k0 + ki][tt];
#pragma unroll
      for (int jq = 0; jq < 6; jq++)
        acc[jq] = fmaf(a, Ws[ki][tm + jq * 16], acc[jq]);
    }
    __syncthreads();
  }
#pragma unroll
  for (int jq = 0; jq < 6; jq++) {
    int p = tm + jq * 16;
    Os[p][tt] = acc[jq] + pb[p];
  }
  __syncthreads();
  for (int i = 0; i < 6; i++) {
    int e = tid + i * 256;
    int vi = e & 15, p = e >> 4;
    out[((size_t)b * 96 + p) * 1024 + v0 + vi] = Os[p][vi];
  }
}

// ---------------------------------------------------------------------------
extern "C" void kernel_launch(void* const* d_in, const int* in_sizes, int n_in,
                              void* d_out, int out_size, void* d_ws, size_t ws_size,
                              hipStream_t stream) {
  (void)in_sizes; (void)n_in; (void)out_size; (void)ws_size;
  const float* x_enc  = (const float*)d_in[0];
  const float* x_mark = (const float*)d_in[1];
  const float* emb_w  = (const float*)d_in[4];
  const float* emb_b  = (const float*)d_in[5];
  const float* ipw    = (const float*)d_in[6];
  const float* cw     = (const float*)d_in[7];
  const float* cb     = (const float*)d_in[8];
  const float* xpw    = (const float*)d_in[9];
  const float* dpw    = (const float*)d_in[10];
  const float* dpb    = (const float*)d_in[11];
  const float* A_log  = (const float*)d_in[12];
  const float* Dpar   = (const float*)d_in[13];
  const float* opw    = (const float*)d_in[14];
  const float* n1w    = (const float*)d_in[15];
  const float* n1b    = (const float*)d_in[16];
  const float* n2w    = (const float*)d_in[17];
  const float* n2b    = (const float*)d_in[18];
  const float* fw1    = (const float*)d_in[19];
  const float* fb1    = (const float*)d_in[20];
  const float* fw2    = (const float*)d_in[21];
  const float* fb2    = (const float*)d_in[22];
  const float* fnw    = (const float*)d_in[23];
  const float* fnb    = (const float*)d_in[24];
  const float* pw     = (const float*)d_in[25];
  const float* pb     = (const float*)d_in[26];

  float* ws   = (float*)d_ws;
  float* H    = ws + OFF_H;
  float* H1   = ws + OFF_H1;
  float* XZ   = ws + OFF_XZ;
  float* XCT  = ws + OFF_XCT;
  float* DLT  = ws + OFF_DLT;
  float* BmT  = ws + OFF_BMT;
  float* CmT  = ws + OFF_CMT;
  float* YT   = ws + OFF_YT;
  float* sumH = ws + OFF_H1;             // overlay: H1 unused during scan
  float* sumP = ws + OFF_H1 + SZ_SUM;

  k_embed<<<dim3(33, 8), 128, 0, stream>>>(x_enc, x_mark, emb_w, emb_b, H);
  for (int l = 0; l < 2; l++) {
    k_xz<<<dim3(33, 8, 4), 128, 0, stream>>>(H, ipw, XZ, l);
    k_mid<<<dim3(34, 8, 2), 256, 0, stream>>>(XZ, cw, cb, xpw, dpw, dpb,
                                              XCT, DLT, BmT, CmT, l);
    k_scan1<<<dim3(16, 8, 32), 64, 0, stream>>>(DLT, XCT, BmT, A_log,
                                                sumH, sumP, l);
    k_scan2<<<dim3(16, 8, 32), 64, 0, stream>>>(DLT, XCT, BmT, CmT, XZ,
                                                A_log, Dpar, sumH, sumP, YT, l);
    k_out<<<dim3(33, 8), 128, 0, stream>>>(YT, H, opw, n1w, n1b, H1, l);
    k_ffn<<<dim3(33, 8), 128, 0, stream>>>(H1, fw1, fb1, fw2, fb2, n2w, n2b, H, l);
  }
  k_final<<<dim3(64, 8), 256, 0, stream>>>(H, fnw, fnb, pw, pb, (float*)d_out);
}

// Round 8
// 399.244 us; speedup vs baseline: 1.5641x; 1.3010x over previous
//
#include <hip/hip_runtime.h>
#include <math.h>

// ---------------------------------------------------------------------------
// Bidirectional Mamba encoder, round 8: bf16 MFMA GEMMs.
// k_embed / k_xz / k_out / k_ffn: 32x128 output tile, 256 thr (4 waves),
// full K=128 panel staged to LDS as bf16 (one barrier per panel), then
// mfma_f32_16x16x32_bf16. Wave w: rows (w&1)*16, cols (w>>1)*64 (4 n-tiles).
// Verified mappings (learn_hip m89/m120): A[m=lane&15][k=q*8+j],
// B^T[n=lane&15][k=q*8+j], D col=lane&15, row=q*4+reg.
// scan2 writes Y[t][d] so k_out stages A transpose-free.
// k_mid / k_scan1 / k_final: round-5/7 proven fp32 versions.
// ---------------------------------------------------------------------------

#define L_SEQ 1031
#define LP    1088          // 16 chunks x 68
#define TC    68
#define NCH   16
#define BATCH 8
#define NVAR  1024
#define SEQQ  512
#define TFEAT 7

#define SZ_H    ((size_t)BATCH * L_SEQ * 128)
#define SZ_XZ   ((size_t)2 * BATCH * L_SEQ * 256)
#define SZ_DT   ((size_t)2 * BATCH * 128 * LP)
#define SZ_BC   ((size_t)2 * BATCH * 16 * LP)
#define OFF_H    ((size_t)0)
#define OFF_H1   (OFF_H + SZ_H)
#define OFF_XZ   (OFF_H1 + SZ_H)
#define OFF_XCT  (OFF_XZ + SZ_XZ)
#define OFF_DLT  (OFF_XCT + SZ_DT)
#define OFF_BMT  (OFF_DLT + SZ_DT)
#define OFF_CMT  (OFF_BMT + SZ_BC)
#define OFF_YT   (OFF_CMT + SZ_BC)
#define SZ_SUM  ((size_t)2 * BATCH * NCH * 128 * 16)   // 524,288 floats

typedef __bf16 bf16_t;
typedef bf16_t bf16x4 __attribute__((ext_vector_type(4)));
typedef bf16_t bf16x8 __attribute__((ext_vector_type(8)));
typedef float floatx4 __attribute__((ext_vector_type(4)));

#define MFMA16(a, b, c) __builtin_amdgcn_mfma_f32_16x16x32_bf16((a), (b), (c), 0, 0, 0)

__device__ __forceinline__ float silu_f(float x) {
  return x / (1.f + __expf(-x));
}
__device__ __forceinline__ float softplus_f(float x) {
  return (x > 20.f) ? x : log1pf(__expf(x));
}
__device__ __forceinline__ float red8(float x) {
  x += __int_as_float(__builtin_amdgcn_update_dpp(
      0, __float_as_int(x), 0xB1, 0xF, 0xF, true));   // quad_perm [1,0,3,2]
  x += __int_as_float(__builtin_amdgcn_update_dpp(
      0, __float_as_int(x), 0x4E, 0xF, 0xF, true));   // quad_perm [2,3,0,1]
  x += __int_as_float(__builtin_amdgcn_update_dpp(
      0, __float_as_int(x), 0x141, 0xF, 0xF, true));  // row_half_mirror
  return x;
}

// Wave/lane decomposition used by all MFMA kernels (256-thread block):
//   lane = tid&63, ln = lane&15, q = lane>>4, w = tid>>6,
//   rw = w&1 (row half), cw = w>>1 (col half), arow = rw*16+ln, wcol = cw*64.
// Output element (r, nt): row rw*16+q*4+r, col wcol+nt*16+ln.

// Stage 128xK-chunk of a row-major [N][K] fp32 weight into Wbf (bf16).
#define STAGE_W128(WBUF, SRC, LDK, K0)                                       \
  _Pragma("unroll")                                                          \
  for (int i_ = 0; i_ < 16; i_++) {                                          \
    int e_ = tid + i_ * 256;                                                 \
    int n_ = e_ >> 5, kq_ = e_ & 31;                                         \
    float4 wv_ = *(const float4*)&(SRC)[(size_t)n_ * (LDK) + (K0) + kq_ * 4];\
    bf16x4 bv_ = {(bf16_t)wv_.x, (bf16_t)wv_.y, (bf16_t)wv_.z, (bf16_t)wv_.w};\
    *(bf16x4*)&WBUF[n_][kq_ * 4] = bv_;                                      \
  }

// 16 MFMAs: full K=128 panel for this wave's 16x64 output.
#define MFMA_K128(ABUF, WBUF, ACC)                                           \
  _Pragma("unroll")                                                          \
  for (int kc_ = 0; kc_ < 4; kc_++) {                                        \
    bf16x8 a_ = *(const bf16x8*)&ABUF[arow][kc_ * 32 + q8];                  \
    _Pragma("unroll")                                                        \
    for (int nt_ = 0; nt_ < 4; nt_++) {                                      \
      bf16x8 b_ = *(const bf16x8*)&WBUF[wcol + nt_ * 16 + ln][kc_ * 32 + q8];\
      ACC[nt_] = MFMA16(a_, b_, ACC[nt_]);                                   \
    }                                                                        \
  }

// ---------------------------------------------------------------------------
// k_embed: H[b,v,:] = token(b,v,:) @ emb_w.T + emb_b. K=512 (4 panels of 128).
// grid (33, 8), block 256.
// ---------------------------------------------------------------------------
__global__ __launch_bounds__(256) void k_embed(
    const float* __restrict__ x_enc, const float* __restrict__ x_mark,
    const float* __restrict__ emb_w, const float* __restrict__ emb_b,
    float* __restrict__ H) {
  int b = blockIdx.y;
  int v0 = blockIdx.x * 32;
  int tid = threadIdx.x;
  __shared__ bf16_t Abf[32][136];
  __shared__ bf16_t Wbf[128][136];
  int lane = tid & 63, ln = lane & 15, q = lane >> 4, q8 = q * 8;
  int w = tid >> 6, rw = w & 1, cw = w >> 1;
  int arow = rw * 16 + ln, wcol = cw * 64;
  floatx4 acc[4];
#pragma unroll
  for (int nt = 0; nt < 4; nt++) acc[nt] = (floatx4){0.f, 0.f, 0.f, 0.f};

  for (int c = 0; c < 4; c++) {
    int s0 = c * 128;
    // A: transpose-stage token(b, v, s) -> Abf[v][s]
#pragma unroll
    for (int i = 0; i < 4; i++) {
      int e = tid + i * 256;
      int s = e >> 3, vq = e & 7;
      int vg = v0 + vq * 4;
      float4 xv;
      if (vg + 3 < NVAR) {
        xv = *(const float4*)&x_enc[((size_t)b * SEQQ + s0 + s) * NVAR + vg];
        if (xv.x == -9999.f) xv.x = -1.f;
        if (xv.y == -9999.f) xv.y = -1.f;
        if (xv.z == -9999.f) xv.z = -1.f;
        if (xv.w == -9999.f) xv.w = -1.f;
      } else {
        float tmp[4];
#pragma unroll
        for (int u = 0; u < 4; u++) {
          int v = vg + u;
          tmp[u] = (v < L_SEQ)
                       ? x_mark[((size_t)b * SEQQ + s0 + s) * TFEAT + (v - NVAR)]
                       : 0.f;
        }
        xv = make_float4(tmp[0], tmp[1], tmp[2], tmp[3]);
      }
      Abf[vq * 4 + 0][s] = (bf16_t)xv.x;
      Abf[vq * 4 + 1][s] = (bf16_t)xv.y;
      Abf[vq * 4 + 2][s] = (bf16_t)xv.z;
      Abf[vq * 4 + 3][s] = (bf16_t)xv.w;
    }
    STAGE_W128(Wbf, emb_w, SEQQ, s0);
    __syncthreads();
    MFMA_K128(Abf, Wbf, acc);
    __syncthreads();
  }
#pragma unroll
  for (int r = 0; r < 4; r++) {
    int v = v0 + rw * 16 + q * 4 + r;
    if (v < L_SEQ) {
      float* dst = &H[((size_t)b * L_SEQ + v) * 128];
#pragma unroll
      for (int nt = 0; nt < 4; nt++) {
        int col = wcol + nt * 16 + ln;
        dst[col] = acc[nt][r] + emb_b[col];
      }
    }
  }
}

// ---------------------------------------------------------------------------
// k_xz: XZ[dir,b,t,nh*128:+128] = h_dir(b,t,:) @ ipw[l,dir,nh].T. K=128.
// grid (33, 8, 4) z=(dir,nh), block 256.
// ---------------------------------------------------------------------------
__global__ __launch_bounds__(256) void k_xz(
    const float* __restrict__ H, const float* __restrict__ ipw,
    float* __restrict__ XZ, int l) {
  int b = blockIdx.y;
  int dir = blockIdx.z >> 1, nh = blockIdx.z & 1;
  int t0 = blockIdx.x * 32;
  int tid = threadIdx.x;
  __shared__ bf16_t Abf[32][136];
  __shared__ bf16_t Wbf[128][136];
  int lane = tid & 63, ln = lane & 15, q = lane >> 4, q8 = q * 8;
  int w = tid >> 6, rw = w & 1, cw = w >> 1;
  int arow = rw * 16 + ln, wcol = cw * 64;
  floatx4 acc[4];
#pragma unroll
  for (int nt = 0; nt < 4; nt++) acc[nt] = (floatx4){0.f, 0.f, 0.f, 0.f};
  const float* wbase = ipw + (size_t)(l * 2 + dir) * 256 * 128 + (size_t)nh * 128 * 128;

#pragma unroll
  for (int i = 0; i < 4; i++) {
    int e = tid + i * 256;
    int tl = e >> 5, kq = e & 31;
    int t = t0 + tl;
    float4 hv = make_float4(0.f, 0.f, 0.f, 0.f);
    if (t < L_SEQ) {
      int st = dir ? (L_SEQ - 1 - t) : t;
      hv = *(const float4*)&H[((size_t)b * L_SEQ + st) * 128 + kq * 4];
    }
    bf16x4 av = {(bf16_t)hv.x, (bf16_t)hv.y, (bf16_t)hv.z, (bf16_t)hv.w};
    *(bf16x4*)&Abf[tl][kq * 4] = av;
  }
  STAGE_W128(Wbf, wbase, 128, 0);
  __syncthreads();
  MFMA_K128(Abf, Wbf, acc);

#pragma unroll
  for (int r = 0; r < 4; r++) {
    int t = t0 + rw * 16 + q * 4 + r;
    if (t < L_SEQ) {
      float* dst = XZ + ((size_t)(dir * BATCH + b) * L_SEQ + t) * 256 + nh * 128;
#pragma unroll
      for (int nt = 0; nt < 4; nt++) dst[wcol + nt * 16 + ln] = acc[nt][r];
    }
  }
}

// ---------------------------------------------------------------------------
// k_mid  (round-5, proven; grid (34,8,2) covers LP=1088)
// ---------------------------------------------------------------------------
__global__ __launch_bounds__(256) void k_mid(
    const float* __restrict__ XZ,
    const float* __restrict__ conv_w, const float* __restrict__ conv_b,
    const float* __restrict__ xpw,
    const float* __restrict__ dpw, const float* __restrict__ dpb,
    float* __restrict__ XCT, float* __restrict__ DLT,
    float* __restrict__ BmT, float* __restrict__ CmT, int l) {
  int b = blockIdx.y, dir = blockIdx.z;
  int t0 = blockIdx.x * 32;
  int tid = threadIdx.x;
  int pg = l * 2 + dir;
  __shared__ float xcs[32][132];
  __shared__ float xpws[40][128];
  __shared__ float dbcs[40][36];
  const float* xz = XZ + (size_t)(dir * BATCH + b) * L_SEQ * 256;

  for (int i = 0; i < 20; i++) {
    int e = tid + i * 256;
    int k = e & 127, j = e >> 7;
    xpws[j][k] = xpw[((size_t)pg * 40 + j) * 128 + k];
  }
  for (int i = 0; i < 16; i++) {
    int e = tid + i * 256;
    int d = e & 127, tl = e >> 7;
    int t = t0 + tl;
    float v = 0.f;
    if (t < L_SEQ) {
      float x1 = xz[(size_t)t * 256 + d];
      float x0 = (t > 0) ? xz[(size_t)(t - 1) * 256 + d] : 0.f;
      float c0 = conv_w[((size_t)pg * 128 + d) * 2 + 0];
      float c1 = conv_w[((size_t)pg * 128 + d) * 2 + 1];
      v = silu_f(x0 * c0 + x1 * c1 + conv_b[(size_t)pg * 128 + d]);
    }
    xcs[tl][d] = v;
  }
  __syncthreads();
  {
    int tl = tid & 31, jg = tid >> 5;
    float acc[5] = {0.f};
    const float4* xrow = (const float4*)&xcs[tl][0];
    for (int kk = 0; kk < 32; kk++) {
      float4 a = xrow[kk];
#pragma unroll
      for (int jj = 0; jj < 5; jj++) {
        float4 w = ((const float4*)&xpws[jg * 5 + jj][0])[kk];
        acc[jj] = fmaf(a.x, w.x, acc[jj]);
        acc[jj] = fmaf(a.y, w.y, acc[jj]);
        acc[jj] = fmaf(a.z, w.z, acc[jj]);
        acc[jj] = fmaf(a.w, w.w, acc[jj]);
      }
    }
#pragma unroll
    for (int jj = 0; jj < 5; jj++) dbcs[jg * 5 + jj][tl] = acc[jj];
  }
  __syncthreads();
  for (int i = 0; i < 4; i++) {
    int e = tid + i * 256;
    int tl = e & 31, r = e >> 5;
    int n = r & 15, isC = r >> 4;
    int t = t0 + tl;
    if (t < LP) {
      float v = dbcs[8 + isC * 16 + n][tl];
      float* dst = isC ? CmT : BmT;
      dst[((size_t)(dir * BATCH + b) * 16 + n) * LP + t] = v;
    }
  }
  {
    int d = tid & 127, th = tid >> 7;
    float dw[8];
#pragma unroll
    for (int k = 0; k < 8; k++) dw[k] = dpw[((size_t)pg * 128 + d) * 8 + k];
    float dbv = dpb[(size_t)pg * 128 + d];
    size_t base = ((size_t)(dir * BATCH + b) * 128 + d) * LP;
    for (int tb = th * 16; tb < th * 16 + 16; tb += 4) {
      int t = t0 + tb;
      if (t < LP) {
        float dv[4], xv[4];
#pragma unroll
        for (int u = 0; u < 4; u++) {
          int tl = tb + u;
          float a = dbv;
#pragma unroll
          for (int k = 0; k < 8; k++) a = fmaf(dbcs[k][tl], dw[k], a);
          dv[u] = softplus_f(a);
          xv[u] = xcs[tl][d];
        }
        *(float4*)(DLT + base + t) = make_float4(dv[0], dv[1], dv[2], dv[3]);
        *(float4*)(XCT + base + t) = make_float4(xv[0], xv[1], xv[2], xv[3]);
      }
    }
  }
}

// ---------------------------------------------------------------------------
// k_scan1  (round-5, proven)
// ---------------------------------------------------------------------------
__global__ __launch_bounds__(64) void k_scan1(
    const float* __restrict__ DLT, const float* __restrict__ XCT,
    const float* __restrict__ BmT,
    const float* __restrict__ A_log,
    float* __restrict__ sumH, float* __restrict__ sumP, int l) {
  int z = blockIdx.z;
  int dir = z >> 4, j = z & 15;
  int b = blockIdx.y;
  int lane = threadIdx.x;
  int np = lane & 7, ds = lane >> 3;
  int d = blockIdx.x * 8 + ds;
  int pg = l * 2 + dir;
  int n0 = np * 2;
  float A0 = -__expf(A_log[((size_t)pg * 128 + d) * 16 + n0]);
  float A1 = -__expf(A_log[((size_t)pg * 128 + d) * 16 + n0 + 1]);
  size_t bd = ((size_t)(dir * BATCH + b) * 128 + d) * LP + (size_t)j * TC;
  size_t bn = ((size_t)(dir * BATCH + b) * 16 + n0) * LP + (size_t)j * TC;
  const float4* dl4 = (const float4*)(DLT + bd);
  const float4* xc4 = (const float4*)(XCT + bd);
  const float4* b04 = (const float4*)(BmT + bn);
  const float4* b14 = (const float4*)(BmT + bn + LP);
  float h0 = 0.f, h1 = 0.f, sdl = 0.f;
  const int NI = TC / 4;   // 17
  float4 cd = dl4[0], cx = xc4[0], cb0 = b04[0], cb1 = b14[0];
#define P1STEP(DL, XC, B0, B1)                       \
  {                                                  \
    float du_ = (DL) * (XC);                         \
    h0 = fmaf(__expf((DL) * A0), h0, du_ * (B0));    \
    h1 = fmaf(__expf((DL) * A1), h1, du_ * (B1));    \
  }
  for (int i = 0; i < NI; i++) {
    float4 nd = cd, nx = cx, nb0 = cb0, nb1 = cb1;
    if (i + 1 < NI) {
      nd = dl4[i + 1]; nx = xc4[i + 1];
      nb0 = b04[i + 1]; nb1 = b14[i + 1];
    }
    P1STEP(cd.x, cx.x, cb0.x, cb1.x);
    P1STEP(cd.y, cx.y, cb0.y, cb1.y);
    P1STEP(cd.z, cx.z, cb0.z, cb1.z);
    P1STEP(cd.w, cx.w, cb0.w, cb1.w);
    sdl += (cd.x + cd.y) + (cd.z + cd.w);
    cd = nd; cx = nx; cb0 = nb0; cb1 = nb1;
  }
#undef P1STEP
  size_t si = (((size_t)(dir * BATCH + b) * NCH + j) * 128 + d) * 16 + n0;
  *(float2*)&sumH[si] = make_float2(h0, h1);
  *(float2*)&sumP[si] = make_float2(__expf(A0 * sdl), __expf(A1 * sdl));
}

// ---------------------------------------------------------------------------
// k_scan2  (round-5 core; writes now go to Y[t][d] layout for k_out)
// ---------------------------------------------------------------------------
__global__ __launch_bounds__(64) void k_scan2(
    const float* __restrict__ DLT, const float* __restrict__ XCT,
    const float* __restrict__ BmT, const float* __restrict__ CmT,
    const float* __restrict__ XZ,
    const float* __restrict__ A_log, const float* __restrict__ Dpar,
    const float* __restrict__ sumH, const float* __restrict__ sumP,
    float* __restrict__ YT, int l) {
  int z = blockIdx.z;
  int dir = z >> 4, j = z & 15;
  int b = blockIdx.y;
  int lane = threadIdx.x;
  int np = lane & 7, ds = lane >> 3;
  int d = blockIdx.x * 8 + ds;
  int pg = l * 2 + dir;
  int n0 = np * 2;
  float A0 = -__expf(A_log[((size_t)pg * 128 + d) * 16 + n0]);
  float A1 = -__expf(A_log[((size_t)pg * 128 + d) * 16 + n0 + 1]);
  float Dv = Dpar[(size_t)pg * 128 + d];
  float h0 = 0.f, h1 = 0.f;
  {
    size_t sbase = ((size_t)(dir * BATCH + b) * NCH) * 2048 + (size_t)d * 16 + n0;
    for (int jj = 0; jj < j; jj++) {
      float2 hE = *(const float2*)&sumH[sbase + (size_t)jj * 2048];
      float2 Pp = *(const float2*)&sumP[sbase + (size_t)jj * 2048];
      h0 = fmaf(Pp.x, h0, hE.x);
      h1 = fmaf(Pp.y, h1, hE.y);
    }
  }
  size_t bd = ((size_t)(dir * BATCH + b) * 128 + d) * LP + (size_t)j * TC;
  size_t bn = ((size_t)(dir * BATCH + b) * 16 + n0) * LP + (size_t)j * TC;
  const float4* dl4 = (const float4*)(DLT + bd);
  const float4* xc4 = (const float4*)(XCT + bd);
  const float4* b04 = (const float4*)(BmT + bn);
  const float4* b14 = (const float4*)(BmT + bn + LP);
  const float4* c04 = (const float4*)(CmT + bn);
  const float4* c14 = (const float4*)(CmT + bn + LP);
  const float* zbase = XZ + (size_t)(dir * BATCH + b) * L_SEQ * 256 + 128 + d
                       + (size_t)j * TC * 256;
  // Y in [t][d] layout:
  float* ybase = YT + ((size_t)(dir * BATCH + b) * LP + (size_t)j * TC) * 128 + d;
  const int NI = TC / 4;   // 17
  float4 cd = dl4[0], cx = xc4[0], cb0 = b04[0], cb1 = b14[0];
  float4 cc0 = c04[0], cc1 = c14[0];
  float zc[4], zn[4];
  if (np == 0) {
#pragma unroll
    for (int u = 0; u < 4; u++) zc[u] = zbase[(size_t)u * 256];
  }
#define STEP1(DL, XC, B0, B1, C0, C1, YO)            \
  {                                                  \
    float du_ = (DL) * (XC);                         \
    h0 = fmaf(__expf((DL) * A0), h0, du_ * (B0));    \
    h1 = fmaf(__expf((DL) * A1), h1, du_ * (B1));    \
    float p_ = red8(fmaf(h1, (C1), h0 * (C0)));      \
    (YO) = fmaf(Dv, (XC), p_);                       \
  }
  for (int i = 0; i < NI; i++) {
    float4 nd = cd, nx = cx, nb0 = cb0, nb1 = cb1, nc0 = cc0, nc1 = cc1;
    if (i + 1 < NI) {
      nd = dl4[i + 1]; nx = xc4[i + 1];
      nb0 = b04[i + 1]; nb1 = b14[i + 1];
      nc0 = c04[i + 1]; nc1 = c14[i + 1];
      if (np == 0) {
        int tb = (i + 1) * 4;
#pragma unroll
        for (int u = 0; u < 4; u++) zn[u] = zbase[(size_t)(tb + u) * 256];
      }
    }
    float4 y;
    STEP1(cd.x, cx.x, cb0.x, cb1.x, cc0.x, cc1.x, y.x);
    STEP1(cd.y, cx.y, cb0.y, cb1.y, cc0.y, cc1.y, y.y);
    STEP1(cd.z, cx.z, cb0.z, cb1.z, cc0.z, cc1.z, y.z);
    STEP1(cd.w, cx.w, cb0.w, cb1.w, cc0.w, cc1.w, y.w);
    if (np == 0) {
      y.x *= silu_f(zc[0]);
      y.y *= silu_f(zc[1]);
      y.z *= silu_f(zc[2]);
      y.w *= silu_f(zc[3]);
      int tb = i * 4;
      ybase[(size_t)(tb + 0) * 128] = y.x;
      ybase[(size_t)(tb + 1) * 128] = y.y;
      ybase[(size_t)(tb + 2) * 128] = y.z;
      ybase[(size_t)(tb + 3) * 128] = y.w;
#pragma unroll
      for (int u = 0; u < 4; u++) zc[u] = zn[u];
    }
    cd = nd; cx = nx; cb0 = nb0; cb1 = nb1; cc0 = nc0; cc1 = nc1;
  }
#undef STEP1
}

// ---------------------------------------------------------------------------
// k_out: H1 = LN1( H + Yf@opw_f.T + Yr@opw_r.T ). Two K=128 panels (dirs).
// grid (33, 8), block 256. LN via in-quad shfl + 512B cross-wave LDS.
// ---------------------------------------------------------------------------
__global__ __launch_bounds__(256) void k_out(
    const float* __restrict__ YT, const float* __restrict__ Hin,
    const float* __restrict__ opw,
    const float* __restrict__ n1w, const float* __restrict__ n1b,
    float* __restrict__ H1, int l) {
  int b = blockIdx.y;
  int t0 = blockIdx.x * 32;
  int tid = threadIdx.x;
  __shared__ bf16_t Abf[32][136];
  __shared__ bf16_t Wbf[128][136];
  __shared__ float Ssum[2][32][2];
  int lane = tid & 63, ln = lane & 15, q = lane >> 4, q8 = q * 8;
  int w = tid >> 6, rw = w & 1, cw = w >> 1;
  int arow = rw * 16 + ln, wcol = cw * 64;
  floatx4 acc[4];
#pragma unroll
  for (int nt = 0; nt < 4; nt++) acc[nt] = (floatx4){0.f, 0.f, 0.f, 0.f};

  for (int dirp = 0; dirp < 2; dirp++) {
    const float* ysrc = YT + (size_t)(dirp * BATCH + b) * LP * 128;
#pragma unroll
    for (int i = 0; i < 4; i++) {
      int e = tid + i * 256;
      int tl = e >> 5, dq = e & 31;
      int tg = t0 + tl;
      int srow = dirp ? (L_SEQ - 1 - tg) : tg;
      float4 yv = make_float4(0.f, 0.f, 0.f, 0.f);
      if (srow >= 0) yv = *(const float4*)&ysrc[(size_t)srow * 128 + dq * 4];
      bf16x4 av = {(bf16_t)yv.x, (bf16_t)yv.y, (bf16_t)yv.z, (bf16_t)yv.w};
      *(bf16x4*)&Abf[tl][dq * 4] = av;
    }
    const float* wsrc = opw + (size_t)(l * 2 + dirp) * 128 * 128;
    STAGE_W128(Wbf, wsrc, 128, 0);
    __syncthreads();
    MFMA_K128(Abf, Wbf, acc);
    __syncthreads();
  }
  // epilogue: residual + LN
  const float* nw = n1w + l * 128;
  const float* nbv = n1b + l * 128;
  float vres[4][4];   // [r][nt]
  float s1r[4], s2r[4];
#pragma unroll
  for (int r = 0; r < 4; r++) {
    int t = t0 + rw * 16 + q * 4 + r;
    float s1 = 0.f, s2 = 0.f;
#pragma unroll
    for (int nt = 0; nt < 4; nt++) {
      int col = wcol + nt * 16 + ln;
      float resid = (t < L_SEQ) ? Hin[((size_t)b * L_SEQ + t) * 128 + col] : 0.f;
      float v = acc[nt][r] + resid;
      vres[r][nt] = v;
      s1 += v;
      s2 += v * v;
    }
#pragma unroll
    for (int m = 1; m < 16; m <<= 1) {
      s1 += __shfl_xor(s1, m);
      s2 += __shfl_xor(s2, m);
    }
    s1r[r] = s1; s2r[r] = s2;
  }
  if (ln == 0) {
#pragma unroll
    for (int r = 0; r < 4; r++) {
      Ssum[cw][rw * 16 + q * 4 + r][0] = s1r[r];
      Ssum[cw][rw * 16 + q * 4 + r][1] = s2r[r];
    }
  }
  __syncthreads();
#pragma unroll
  for (int r = 0; r < 4; r++) {
    int row = rw * 16 + q * 4 + r;
    float s1 = s1r[r] + Ssum[cw ^ 1][row][0];
    float s2 = s2r[r] + Ssum[cw ^ 1][row][1];
    float mean = s1 * (1.f / 128.f);
    float rstd = rsqrtf(s2 * (1.f / 128.f) - mean * mean + 1e-5f);
    int t = t0 + row;
    if (t < L_SEQ) {
#pragma unroll
      for (int nt = 0; nt < 4; nt++) {
        int col = wcol + nt * 16 + ln;
        H1[((size_t)b * L_SEQ + t) * 128 + col] =
            (vres[r][nt] - mean) * rstd * nw[col] + nbv[col];
      }
    }
  }
}

// ---------------------------------------------------------------------------
// k_ffn: H = LN2( h1 + relu(h1@w1.T+b1)@w2.T + b2 ). Two K=128 MFMA panels.
// grid (33, 8), block 256.
// ---------------------------------------------------------------------------
__global__ __launch_bounds__(256) void k_ffn(
    const float* __restrict__ H1, const float* __restrict__ w1,
    const float* __restrict__ b1, const float* __restrict__ w2,
    const float* __restrict__ b2, const float* __restrict__ n2w,
    const float* __restrict__ n2b, float* __restrict__ Hout, int l) {
  int b = blockIdx.y;
  int t0 = blockIdx.x * 32;
  int tid = threadIdx.x;
  __shared__ bf16_t Abf[32][136];
  __shared__ bf16_t Wbf[128][136];
  __shared__ bf16_t Ut[32][136];
  __shared__ float Ssum[2][32][2];
  int lane = tid & 63, ln = lane & 15, q = lane >> 4, q8 = q * 8;
  int w = tid >> 6, rw = w & 1, cw = w >> 1;
  int arow = rw * 16 + ln, wcol = cw * 64;
  floatx4 acc[4];
#pragma unroll
  for (int nt = 0; nt < 4; nt++) acc[nt] = (floatx4){0.f, 0.f, 0.f, 0.f};
  const float* w1b = w1 + (size_t)l * 128 * 128;
  const float* w2b = w2 + (size_t)l * 128 * 128;

  // GEMM1: A = H1 tile, W = w1
#pragma unroll
  for (int i = 0; i < 4; i++) {
    int e = tid + i * 256;
    int tl = e >> 5, kq = e & 31;
    int t = t0 + tl;
    float4 hv = make_float4(0.f, 0.f, 0.f, 0.f);
    if (t < L_SEQ)
      hv = *(const float4*)&H1[((size_t)b * L_SEQ + t) * 128 + kq * 4];
    bf16x4 av = {(bf16_t)hv.x, (bf16_t)hv.y, (bf16_t)hv.z, (bf16_t)hv.w};
    *(bf16x4*)&Abf[tl][kq * 4] = av;
  }
  STAGE_W128(Wbf, w1b, 128, 0);
  __syncthreads();
  MFMA_K128(Abf, Wbf, acc);
  __syncthreads();
  // mid: relu(+b1) -> Ut (bf16), restage W = w2
  {
    float b1v[4];
#pragma unroll
    for (int nt = 0; nt < 4; nt++) b1v[nt] = b1[l * 128 + wcol + nt * 16 + ln];
#pragma unroll
    for (int nt = 0; nt < 4; nt++) {
#pragma unroll
      for (int r = 0; r < 4; r++) {
        Ut[rw * 16 + q * 4 + r][wcol + nt * 16 + ln] =
            (bf16_t)fmaxf(acc[nt][r] + b1v[nt], 0.f);
      }
      acc[nt] = (floatx4){0.f, 0.f, 0.f, 0.f};
    }
  }
  STAGE_W128(Wbf, w2b, 128, 0);
  __syncthreads();
  // GEMM2: A = Ut, W = w2
  MFMA_K128(Ut, Wbf, acc);
  // epilogue: + b2 + residual + LN
  const float* nw = n2w + l * 128;
  const float* nbv = n2b + l * 128;
  float vres[4][4];
  float s1r[4], s2r[4];
#pragma unroll
  for (int r = 0; r < 4; r++) {
    int t = t0 + rw * 16 + q * 4 + r;
    float s1 = 0.f, s2 = 0.f;
#pragma unroll
    for (int nt = 0; nt < 4; nt++) {
      int col = wcol + nt * 16 + ln;
      float resid = (t < L_SEQ) ? H1[((size_t)b * L_SEQ + t) * 128 + col] : 0.f;
      float v = acc[nt][r] + b2[l * 128 + col] + resid;
      vres[r][nt] = v;
      s1 += v;
      s2 += v * v;
    }
#pragma unroll
    for (int m = 1; m < 16; m <<= 1) {
      s1 += __shfl_xor(s1, m);
      s2 += __shfl_xor(s2, m);
    }
    s1r[r] = s1; s2r[r] = s2;
  }
  __syncthreads();   // Ut/Wbf reads done before Ssum overlaps? Ssum separate; barrier orders Ssum writes below
  if (ln == 0) {
#pragma unroll
    for (int r = 0; r < 4; r++) {
      Ssum[cw][rw * 16 + q * 4 + r][0] = s1r[r];
      Ssum[cw][rw * 16 + q * 4 + r][1] = s2r[r];
    }
  }
  __syncthreads();
#pragma unroll
  for (int r = 0; r < 4; r++) {
    int row = rw * 16 + q * 4 + r;
    float s1 = s1r[r] + Ssum[cw ^ 1][row][0];
    float s2 = s2r[r] + Ssum[cw ^ 1][row][1];
    float mean = s1 * (1.f / 128.f);
    float rstd = rsqrtf(s2 * (1.f / 128.f) - mean * mean + 1e-5f);
    int t = t0 + row;
    if (t < L_SEQ) {
#pragma unroll
      for (int nt = 0; nt < 4; nt++) {
        int col = wcol + nt * 16 + ln;
        Hout[((size_t)b * L_SEQ + t) * 128 + col] =
            (vres[r][nt] - mean) * rstd * nw[col] + nbv[col];
      }
    }
  }
}

// ---------------------------------------------------------------------------
// k_final  (round-3, proven)
// ---------------------------------------------------------------------------
__global__ __launch_bounds__(256) void k_final(
    const float* __restrict__ Hsrc, const float* __restrict__ fw,
    const float* __restrict__ fb, const float* __restrict__ pw,
    const float* __restrict__ pb, float* __restrict__ out) {
  int b = blockIdx.y;
  int v0 = blockIdx.x * 16;
  int tid = threadIdx.x;
  __shared__ float At[128][17];
  __shared__ float Ws[32][97];
  __shared__ float Os[96][17];
  for (int i = 0; i < 8; i++) {
    int e = tid + i * 256;
    int k = e & 127, tl = e >> 7;
    At[k][tl] = Hsrc[((size_t)b * L_SEQ + v0 + tl) * 128 + k];
  }
  __syncthreads();
  {
    int g = tid & 15, tl = tid >> 4;
    float s1 = 0.f, s2 = 0.f;
#pragma unroll
    for (int kk = 0; kk < 8; kk++) {
      float v = At[g * 8 + kk][tl];
      s1 += v;
      s2 += v * v;
    }
#pragma unroll
    for (int msk = 1; msk < 16; msk <<= 1) {
      s1 += __shfl_xor(s1, msk);
      s2 += __shfl_xor(s2, msk);
    }
    float mean = s1 * (1.f / 128.f);
    float rstd = rsqrtf(s2 * (1.f / 128.f) - mean * mean + 1e-5f);
#pragma unroll
    for (int kk = 0; kk < 8; kk++) {
      int k = g * 8 + kk;
      At[k][tl] = (At[k][tl] - mean) * rstd * fw[k] + fb[k];
    }
  }
  __syncthreads();
  int tm = tid & 15, tt = tid >> 4;
  float acc[6] = {0.f};
  for (int k0 = 0; k0 < 128; k0 += 32) {
    for (int i = 0; i < 12; i++) {
      int e = tid + i * 256;
      int ki = e & 31, p = e >> 5;
      Ws[ki][p] = pw[(size_t)p * 128 + k0 + ki];
    }
    __syncthreads();
    for (int ki = 0; ki < 32; ki++) {
      float a = At[k0 + ki][tt];
#pragma unroll
      for (int jq = 0; jq < 6; jq++)
        acc[jq] = fmaf(a, Ws[ki][tm + jq * 16], acc[jq]);
    }
    __syncthreads();
  }
#pragma unroll
  for (int jq = 0; jq < 6; jq++) {
    int p = tm + jq * 16;
    Os[p][tt] = acc[jq] + pb[p];
  }
  __syncthreads();
  for (int i = 0; i < 6; i++) {
    int e = tid + i * 256;
    int vi = e & 15, p = e >> 4;
    out[((size_t)b * 96 + p) * 1024 + v0 + vi] = Os[p][vi];
  }
}

// ---------------------------------------------------------------------------
extern "C" void kernel_launch(void* const* d_in, const int* in_sizes, int n_in,
                              void* d_out, int out_size, void* d_ws, size_t ws_size,
                              hipStream_t stream) {
  (void)in_sizes; (void)n_in; (void)out_size; (void)ws_size;
  const float* x_enc  = (const float*)d_in[0];
  const float* x_mark = (const float*)d_in[1];
  const float* emb_w  = (const float*)d_in[4];
  const float* emb_b  = (const float*)d_in[5];
  const float* ipw    = (const float*)d_in[6];
  const float* cw     = (const float*)d_in[7];
  const float* cb     = (const float*)d_in[8];
  const float* xpw    = (const float*)d_in[9];
  const float* dpw    = (const float*)d_in[10];
  const float* dpb    = (const float*)d_in[11];
  const float* A_log  = (const float*)d_in[12];
  const float* Dpar   = (const float*)d_in[13];
  const float* opw    = (const float*)d_in[14];
  const float* n1w    = (const float*)d_in[15];
  const float* n1b    = (const float*)d_in[16];
  const float* n2w    = (const float*)d_in[17];
  const float* n2b    = (const float*)d_in[18];
  const float* fw1    = (const float*)d_in[19];
  const float* fb1    = (const float*)d_in[20];
  const float* fw2    = (const float*)d_in[21];
  const float* fb2    = (const float*)d_in[22];
  const float* fnw    = (const float*)d_in[23];
  const float* fnb    = (const float*)d_in[24];
  const float* pw     = (const float*)d_in[25];
  const float* pb     = (const float*)d_in[26];

  float* ws   = (float*)d_ws;
  float* H    = ws + OFF_H;
  float* H1   = ws + OFF_H1;
  float* XZ   = ws + OFF_XZ;
  float* XCT  = ws + OFF_XCT;
  float* DLT  = ws + OFF_DLT;
  float* BmT  = ws + OFF_BMT;
  float* CmT  = ws + OFF_CMT;
  float* YT   = ws + OFF_YT;
  float* sumH = ws + OFF_H1;             // overlay: H1 unused during scan
  float* sumP = ws + OFF_H1 + SZ_SUM;

  k_embed<<<dim3(33, 8), 256, 0, stream>>>(x_enc, x_mark, emb_w, emb_b, H);
  for (int l = 0; l < 2; l++) {
    k_xz<<<dim3(33, 8, 4), 256, 0, stream>>>(H, ipw, XZ, l);
    k_mid<<<dim3(34, 8, 2), 256, 0, stream>>>(XZ, cw, cb, xpw, dpw, dpb,
                                              XCT, DLT, BmT, CmT, l);
    k_scan1<<<dim3(16, 8, 32), 64, 0, stream>>>(DLT, XCT, BmT, A_log,
                                                sumH, sumP, l);
    k_scan2<<<dim3(16, 8, 32), 64, 0, stream>>>(DLT, XCT, BmT, CmT, XZ,
                                                A_log, Dpar, sumH, sumP, YT, l);
    k_out<<<dim3(33, 8), 256, 0, stream>>>(YT, H, opw, n1w, n1b, H1, l);
    k_ffn<<<dim3(33, 8), 256, 0, stream>>>(H1, fw1, fb1, fw2, fb2, n2w, n2b, H, l);
  }
  k_final<<<dim3(64, 8), 256, 0, stream>>>(H, fnw, fnb, pw, pb, (float*)d_out);
}